// Round 1
// baseline (834.891 us; speedup 1.0000x reference)
//
#include <hip/hip_runtime.h>

// Problem constants (WLN_Edit): B=64, N=512, NB=600, A=89, E=5, H=256, MAX_NB=10, DEPTH=3
constexpr int Bb   = 64;
constexpr int Nn   = 512;
constexpr int NBb  = 600;
constexpr int Ad   = 89;
constexpr int Ed   = 5;
constexpr int Hd   = 256;
constexpr int MNB  = 10;
constexpr int Mrows = Bb * Nn;   // 32768

// ---------------------------------------------------------------------------
// Generic fp32 tiled GEMM: C[M,256] = op( [A1 | A2] @ Bmat (+bias) (relu) )
// A1: [M,K1] row-major (stride K1), A2: [M,Ktot-K1] row-major (stride Ktot-K1)
// Bmat: [Ktot,256] row-major. BM=BN=64, BK=16, 256 threads, 4x4 per thread.
// M and N are exact multiples of 64 (no m/n guards); K guarded for K=89.
// ---------------------------------------------------------------------------
template<bool RELU, bool BIAS>
__global__ __launch_bounds__(256)
void gemm_f32(const float* __restrict__ A1, const float* __restrict__ A2,
              int K1, int Ktot,
              const float* __restrict__ Bmat, const float* __restrict__ bias,
              float* __restrict__ C) {
  constexpr int BM = 64, BN = 64, BK = 16;
  // +8 pad: row stride 72 floats = 288B (16B-aligned for float4 LDS reads),
  // 72 mod 32 = 8 banks of skew per row.
  __shared__ float As[BK][BM + 8];
  __shared__ float Bs[BK][BN];

  const int tid = threadIdx.x;
  const int tx = tid & 15;        // 0..15 -> col group
  const int ty = tid >> 4;        // 0..15 -> row group
  const int m0 = blockIdx.x * BM;
  const int n0 = blockIdx.y * BN;

  // staging indices
  const int ar = tid >> 2;          // 0..63  A-tile row
  const int ac = (tid & 3) * 4;     // 0,4,8,12  A-tile col base
  const int br = tid >> 4;          // 0..15  B-tile row
  const int bc = (tid & 15) * 4;    // B-tile col base

  float acc[4][4] = {};

  const int K2stride = Ktot - K1;

  for (int k0 = 0; k0 < Ktot; k0 += BK) {
    // --- stage A tile (transposed into LDS) ---
#pragma unroll
    for (int j = 0; j < 4; ++j) {
      const int kk = k0 + ac + j;
      float v = 0.f;
      if (kk < K1) {
        v = A1[(size_t)(m0 + ar) * K1 + kk];
      } else if (kk < Ktot) {
        v = A2[(size_t)(m0 + ar) * K2stride + (kk - K1)];
      }
      As[ac + j][ar] = v;
    }
    // --- stage B tile ---
    {
      const int kk = k0 + br;
      float4 v = make_float4(0.f, 0.f, 0.f, 0.f);
      if (kk < Ktot) {
        v = *reinterpret_cast<const float4*>(&Bmat[(size_t)kk * Hd + n0 + bc]);
      }
      *reinterpret_cast<float4*>(&Bs[br][bc]) = v;
    }
    __syncthreads();

#pragma unroll
    for (int kk = 0; kk < BK; ++kk) {
      const float4 a4 = *reinterpret_cast<const float4*>(&As[kk][ty * 4]);
      const float4 b4 = *reinterpret_cast<const float4*>(&Bs[kk][tx * 4]);
      const float a_[4] = {a4.x, a4.y, a4.z, a4.w};
      const float b_[4] = {b4.x, b4.y, b4.z, b4.w};
#pragma unroll
      for (int i = 0; i < 4; ++i)
#pragma unroll
        for (int j = 0; j < 4; ++j)
          acc[i][j] = fmaf(a_[i], b_[j], acc[i][j]);
    }
    __syncthreads();
  }

  // --- epilogue ---
#pragma unroll
  for (int i = 0; i < 4; ++i) {
    const int m = m0 + ty * 4 + i;
    float vv[4];
#pragma unroll
    for (int j = 0; j < 4; ++j) {
      const int n = n0 + tx * 4 + j;
      float v = acc[i][j];
      if constexpr (BIAS) v += bias[n];
      if constexpr (RELU) v = fmaxf(v, 0.f);
      vv[j] = v;
    }
    *reinterpret_cast<float4*>(&C[(size_t)m * Hd + n0 + tx * 4]) =
        make_float4(vv[0], vv[1], vv[2], vv[3]);
  }
}

// ---------------------------------------------------------------------------
// Fused neighbor kernel:
// NEI[m,h] = sum_{k < num_nbs[m]} relu( T[b, ai(m,k), h]
//                                       + sum_e bond[b, bi(m,k), e]*W_U2[256+e, h]
//                                       + b_U2[h] )
// One block of 256 threads handles 8 consecutive rows m; thread = h.
// ---------------------------------------------------------------------------
__global__ __launch_bounds__(256)
void nei_kernel(const float* __restrict__ T, const float* __restrict__ input_bond,
                const int* __restrict__ atom_graph, const int* __restrict__ bond_graph,
                const int* __restrict__ num_nbs,
                const float* __restrict__ W_U2, const float* __restrict__ b_U2,
                float* __restrict__ NEI) {
  const int h = threadIdx.x;
  const int m0 = blockIdx.x * 8;

  float wb[Ed];
#pragma unroll
  for (int e = 0; e < Ed; ++e) wb[e] = W_U2[(size_t)(Hd + e) * Hd + h];
  const float b2 = b_U2[h];

  for (int r = 0; r < 8; ++r) {
    const int m = m0 + r;
    const int b = m >> 9;                 // / 512
    const int nn = num_nbs[m];
    float acc = 0.f;
    for (int k = 0; k < nn; ++k) {
      const int ai = atom_graph[((size_t)m * MNB + k) * 2 + 1];
      const int bi = bond_graph[((size_t)m * MNB + k) * 2 + 1];
      const float* bp = input_bond + ((size_t)b * NBb + bi) * Ed;
      float dot = b2;
#pragma unroll
      for (int e = 0; e < Ed; ++e) dot = fmaf(bp[e], wb[e], dot);
      const float v = T[(((size_t)b << 9) + (size_t)ai) * Hd + h] + dot;
      acc += fmaxf(v, 0.f);
    }
    NEI[(size_t)m * Hd + h] = acc;
  }
}

extern "C" void kernel_launch(void* const* d_in, const int* in_sizes, int n_in,
                              void* d_out, int out_size, void* d_ws, size_t ws_size,
                              hipStream_t stream) {
  const float* input_atom = (const float*)d_in[0];   // [64,512,89]
  const float* input_bond = (const float*)d_in[1];   // [64,600,5]
  const int*   atom_graph = (const int*)d_in[2];     // [64,512,10,2]
  const int*   bond_graph = (const int*)d_in[3];     // [64,512,10,2]
  const int*   num_nbs    = (const int*)d_in[4];     // [64,512]
  const float* W_atom     = (const float*)d_in[5];   // [89,256]
  const float* W_U2       = (const float*)d_in[6];   // [261,256]
  const float* b_U2       = (const float*)d_in[7];   // [256]
  const float* W_U1       = (const float*)d_in[8];   // [512,256]
  const float* b_U1       = (const float*)d_in[9];   // [256]

  float* out = (float*)d_out;                        // [32768,256]
  float* P   = (float*)d_ws;                         // AF ping buffer
  float* R   = P + (size_t)Mrows * Hd;               // NEI buffer

  dim3 blk(256);
  dim3 g(Mrows / 64, Hd / 64);    // 512 x 4

  // embed: AF0 = input_atom @ W_atom  -> P
  gemm_f32<false, false><<<g, blk, 0, stream>>>(input_atom, nullptr, Ad, Ad,
                                                W_atom, nullptr, P);

  const float* AF = P;      // current atom features
  float* other = out;       // dead buffer usable for T / next AF
  for (int d = 0; d < 3; ++d) {
    float* Tbuf = other;
    // T = AF @ W_U2[:256]   (rows 0..255 of W_U2 are contiguous)
    gemm_f32<false, false><<<g, blk, 0, stream>>>(AF, nullptr, Hd, Hd,
                                                  W_U2, nullptr, Tbuf);
    // NEI = masked sum of relu(gather(T) + bond@W_U2[256:] + b_U2)
    nei_kernel<<<Mrows / 8, blk, 0, stream>>>(Tbuf, input_bond, atom_graph,
                                              bond_graph, num_nbs, W_U2, b_U2, R);
    // AF' = relu([AF | NEI] @ W_U1 + b_U1) -> overwrite Tbuf (T now dead)
    gemm_f32<true, true><<<g, blk, 0, stream>>>(AF, R, Hd, 2 * Hd,
                                                W_U1, b_U1, Tbuf);
    float* newAF = Tbuf;
    other = (float*)AF;
    AF = newAF;
  }
  // After 3 depths AF == d_out (ping-pong parity: P -> out -> P -> out).
}

// Round 2
// 394.378 us; speedup vs baseline: 2.1170x; 2.1170x over previous
//
#include <hip/hip_runtime.h>

// Problem constants (WLN_Edit): B=64, N=512, NB=600, A=89, E=5, H=256, MAX_NB=10, DEPTH=3
constexpr int Bb   = 64;
constexpr int Nn   = 512;
constexpr int NBb  = 600;
constexpr int Ad   = 89;
constexpr int Ed   = 5;
constexpr int Hd   = 256;
constexpr int MNB  = 10;
constexpr int Mrows = Bb * Nn;   // 32768

typedef __bf16 bf16x8 __attribute__((ext_vector_type(8)));
typedef float  f32x4  __attribute__((ext_vector_type(4)));

typedef __attribute__((address_space(1))) const void gvoid_t;
typedef __attribute__((address_space(3))) void lvoid_t;

__device__ inline ushort bf_rne(float x) {
  unsigned u = __float_as_uint(x);
  unsigned r = (u + 0x7fffu + ((u >> 16) & 1u)) >> 16;
  return (ushort)r;
}
__device__ inline float bf_f(ushort h) { return __uint_as_float(((unsigned)h) << 16); }

// ---------------------------------------------------------------------------
// Embed GEMM (fp32 vector path, K=89 only): AF0 = input_atom @ W_atom,
// written directly as split bf16 (hi/lo). BM=BN=64, BK=16, 256 thr, 4x4/thr.
// ---------------------------------------------------------------------------
__global__ __launch_bounds__(256)
void embed_gemm(const float* __restrict__ A1, const float* __restrict__ Bmat,
                ushort* __restrict__ Chi, ushort* __restrict__ Clo) {
  constexpr int BM = 64, BN = 64, BK = 16, K1 = Ad;
  __shared__ float As[BK][BM + 8];
  __shared__ float Bs[BK][BN];
  const int tid = threadIdx.x;
  const int tx = tid & 15, ty = tid >> 4;
  const int m0 = blockIdx.x * BM, n0 = blockIdx.y * BN;
  const int ar = tid >> 2, ac = (tid & 3) * 4;
  const int br = tid >> 4, bc = (tid & 15) * 4;
  float acc[4][4] = {};

  for (int k0 = 0; k0 < K1; k0 += BK) {
#pragma unroll
    for (int j = 0; j < 4; ++j) {
      const int kk = k0 + ac + j;
      As[ac + j][ar] = (kk < K1) ? A1[(size_t)(m0 + ar) * K1 + kk] : 0.f;
    }
    {
      const int kk = k0 + br;
      float4 v = make_float4(0.f, 0.f, 0.f, 0.f);
      if (kk < K1) v = *reinterpret_cast<const float4*>(&Bmat[(size_t)kk * Hd + n0 + bc]);
      *reinterpret_cast<float4*>(&Bs[br][bc]) = v;
    }
    __syncthreads();
#pragma unroll
    for (int kk = 0; kk < BK; ++kk) {
      const float4 a4 = *reinterpret_cast<const float4*>(&As[kk][ty * 4]);
      const float4 b4 = *reinterpret_cast<const float4*>(&Bs[kk][tx * 4]);
      const float a_[4] = {a4.x, a4.y, a4.z, a4.w};
      const float b_[4] = {b4.x, b4.y, b4.z, b4.w};
#pragma unroll
      for (int i = 0; i < 4; ++i)
#pragma unroll
        for (int j = 0; j < 4; ++j)
          acc[i][j] = fmaf(a_[i], b_[j], acc[i][j]);
    }
    __syncthreads();
  }

#pragma unroll
  for (int i = 0; i < 4; ++i) {
    const int m = m0 + ty * 4 + i;
    ushort4 h4, l4;
    float v;
    v = acc[i][0]; h4.x = bf_rne(v); l4.x = bf_rne(v - bf_f(h4.x));
    v = acc[i][1]; h4.y = bf_rne(v); l4.y = bf_rne(v - bf_f(h4.y));
    v = acc[i][2]; h4.z = bf_rne(v); l4.z = bf_rne(v - bf_f(h4.z));
    v = acc[i][3]; h4.w = bf_rne(v); l4.w = bf_rne(v - bf_f(h4.w));
    *reinterpret_cast<ushort4*>(&Chi[(size_t)m * Hd + n0 + tx * 4]) = h4;
    *reinterpret_cast<ushort4*>(&Clo[(size_t)m * Hd + n0 + tx * 4]) = l4;
  }
}

// ---------------------------------------------------------------------------
// Weight prep (once per launch): split fp32 weights into hi/lo bf16 and
// TRANSPOSE to [n][k] layout so B-tiles stage identically to A-tiles.
// ---------------------------------------------------------------------------
__global__ __launch_bounds__(256)
void prep_weights(const float* __restrict__ W_U2, const float* __restrict__ W_U1,
                  ushort* __restrict__ w2h, ushort* __restrict__ w2l,
                  ushort* __restrict__ w1ah, ushort* __restrict__ w1al,
                  ushort* __restrict__ w1bh, ushort* __restrict__ w1bl) {
  const int n = blockIdx.x;    // output row (transposed): 0..255
  const int k = threadIdx.x;   // 0..255
  const size_t o = (size_t)n * 256 + k;
  float v; ushort h;
  v = W_U2[(size_t)k * Hd + n];           h = bf_rne(v); w2h[o]  = h; w2l[o]  = bf_rne(v - bf_f(h));
  v = W_U1[(size_t)k * Hd + n];           h = bf_rne(v); w1ah[o] = h; w1al[o] = bf_rne(v - bf_f(h));
  v = W_U1[(size_t)(k + 256) * Hd + n];   h = bf_rne(v); w1bh[o] = h; w1bl[o] = bf_rne(v - bf_f(h));
}

// ---------------------------------------------------------------------------
// MFMA GEMM: C[32768,256] = sum_seg A_seg(M x 256) @ B_seg(256 x 256)
// A segs: bf16 row-major [m][k] stride 256. B segs: bf16 TRANSPOSED [n][k].
// 128x128 tile, BK=32, 4 waves, mfma_f32_16x16x32_bf16, global_load_lds(16B).
// ---------------------------------------------------------------------------
struct SegPtrs { const ushort* a[5]; const ushort* b[5]; };

template<int NSEG, bool RELU, bool BIAS>
__global__ __launch_bounds__(256)
void gemm_mfma(SegPtrs segs, const float* __restrict__ bias, float* __restrict__ C) {
  __shared__ ushort As[128 * 32];
  __shared__ ushort Bs[128 * 32];
  const int tid  = threadIdx.x;
  const int lane = tid & 63;
  const int w    = tid >> 6;
  const int wr   = w >> 1, wc = w & 1;
  const int m0   = blockIdx.x * 128;
  const int n0   = blockIdx.y * 128;
  const int arow = tid >> 2;          // 0..63 tile row per staging round
  const int acol = (tid & 3) * 8;     // element col base within BK=32
  const int fr   = lane & 15;
  const int fq   = lane >> 4;

  f32x4 acc[4][4] = {};

#pragma unroll
  for (int seg = 0; seg < NSEG; ++seg) {
    const ushort* __restrict__ Aseg = segs.a[seg];
    const ushort* __restrict__ Bseg = segs.b[seg];
    for (int k8 = 0; k8 < 8; ++k8) {
      const int kk = k8 * 32;
#pragma unroll
      for (int i = 0; i < 2; ++i) {
        const ushort* ga = Aseg + (size_t)(m0 + arow + 64 * i) * 256 + kk + acol;
        const ushort* gb = Bseg + (size_t)(n0 + arow + 64 * i) * 256 + kk + acol;
        __builtin_amdgcn_global_load_lds((gvoid_t*)ga,
            (lvoid_t*)(As + i * 2048 + w * 512), 16, 0, 0);
        __builtin_amdgcn_global_load_lds((gvoid_t*)gb,
            (lvoid_t*)(Bs + i * 2048 + w * 512), 16, 0, 0);
      }
      __syncthreads();   // drains vmcnt -> LDS tiles ready

      bf16x8 bfr[4];
#pragma unroll
      for (int nf = 0; nf < 4; ++nf)
        bfr[nf] = *reinterpret_cast<const bf16x8*>(&Bs[(wc * 64 + nf * 16 + fr) * 32 + fq * 8]);
#pragma unroll
      for (int mf = 0; mf < 4; ++mf) {
        bf16x8 af = *reinterpret_cast<const bf16x8*>(&As[(wr * 64 + mf * 16 + fr) * 32 + fq * 8]);
#pragma unroll
        for (int nf = 0; nf < 4; ++nf)
          acc[mf][nf] = __builtin_amdgcn_mfma_f32_16x16x32_bf16(af, bfr[nf], acc[mf][nf], 0, 0, 0);
      }
      __syncthreads();   // LDS reads done before next stage overwrites
    }
  }

  // epilogue: C/D layout col=lane&15, row=(lane>>4)*4+reg  [verified m89]
#pragma unroll
  for (int mf = 0; mf < 4; ++mf) {
#pragma unroll
    for (int nf = 0; nf < 4; ++nf) {
      const int col = n0 + wc * 64 + nf * 16 + fr;
      float bv = 0.f;
      if constexpr (BIAS) bv = bias[col];
#pragma unroll
      for (int r = 0; r < 4; ++r) {
        const int row = m0 + wr * 64 + mf * 16 + fq * 4 + r;
        float v = acc[mf][nf][r] + bv;
        if constexpr (RELU) v = fmaxf(v, 0.f);
        C[(size_t)row * Hd + col] = v;
      }
    }
  }
}

// ---------------------------------------------------------------------------
// Fused neighbor kernel: NEI[m,h] = sum_{k<num_nbs} relu(T[gather] + bond·W + b)
// T is fp32 (lives in d_out); NEI written as single bf16 (enters output only
// through 0.01-scale W_U1[256:], so bf16 error is ~1e-5 absolute at output).
// ---------------------------------------------------------------------------
__global__ __launch_bounds__(256)
void nei_kernel(const float* __restrict__ T, const float* __restrict__ input_bond,
                const int* __restrict__ atom_graph, const int* __restrict__ bond_graph,
                const int* __restrict__ num_nbs,
                const float* __restrict__ W_U2, const float* __restrict__ b_U2,
                ushort* __restrict__ NEI) {
  const int h = threadIdx.x;
  const int m0 = blockIdx.x * 8;

  float wb[Ed];
#pragma unroll
  for (int e = 0; e < Ed; ++e) wb[e] = W_U2[(size_t)(Hd + e) * Hd + h];
  const float b2 = b_U2[h];

  for (int r = 0; r < 8; ++r) {
    const int m = m0 + r;
    const int b = m >> 9;
    const int nn = num_nbs[m];
    float acc = 0.f;
    for (int k = 0; k < nn; ++k) {
      const int ai = atom_graph[((size_t)m * MNB + k) * 2 + 1];
      const int bi = bond_graph[((size_t)m * MNB + k) * 2 + 1];
      const float* bp = input_bond + ((size_t)b * NBb + bi) * Ed;
      float dot = b2;
#pragma unroll
      for (int e = 0; e < Ed; ++e) dot = fmaf(bp[e], wb[e], dot);
      const float v = T[(((size_t)b << 9) + (size_t)ai) * Hd + h] + dot;
      acc += fmaxf(v, 0.f);
    }
    NEI[(size_t)m * Hd + h] = bf_rne(acc);
  }
}

// ---------------------------------------------------------------------------
// fp32 -> split bf16 (hi/lo) requantize of AF between depths.
// ---------------------------------------------------------------------------
__global__ __launch_bounds__(256)
void split_convert(const float* __restrict__ x, ushort* __restrict__ hi,
                   ushort* __restrict__ lo) {
  const size_t i = (size_t)blockIdx.x * 256 + threadIdx.x;
  const float4 v = reinterpret_cast<const float4*>(x)[i];
  ushort4 h4, l4;
  h4.x = bf_rne(v.x); l4.x = bf_rne(v.x - bf_f(h4.x));
  h4.y = bf_rne(v.y); l4.y = bf_rne(v.y - bf_f(h4.y));
  h4.z = bf_rne(v.z); l4.z = bf_rne(v.z - bf_f(h4.z));
  h4.w = bf_rne(v.w); l4.w = bf_rne(v.w - bf_f(h4.w));
  reinterpret_cast<ushort4*>(hi)[i] = h4;
  reinterpret_cast<ushort4*>(lo)[i] = l4;
}

extern "C" void kernel_launch(void* const* d_in, const int* in_sizes, int n_in,
                              void* d_out, int out_size, void* d_ws, size_t ws_size,
                              hipStream_t stream) {
  const float* input_atom = (const float*)d_in[0];
  const float* input_bond = (const float*)d_in[1];
  const int*   atom_graph = (const int*)d_in[2];
  const int*   bond_graph = (const int*)d_in[3];
  const int*   num_nbs    = (const int*)d_in[4];
  const float* W_atom     = (const float*)d_in[5];
  const float* W_U2       = (const float*)d_in[6];
  const float* b_U2       = (const float*)d_in[7];
  const float* W_U1       = (const float*)d_in[8];
  const float* b_U1       = (const float*)d_in[9];

  const size_t MH = (size_t)Mrows * Hd;          // 8,388,608 elements
  ushort* AFhi  = (ushort*)d_ws;
  ushort* AFlo  = AFhi + MH;
  ushort* NEIbf = AFlo + MH;
  ushort* w2h   = NEIbf + MH;                    // 6 x 256x256 bf16 weight panels
  ushort* w2l   = w2h  + 256 * 256;
  ushort* w1ah  = w2l  + 256 * 256;
  ushort* w1al  = w1ah + 256 * 256;
  ushort* w1bh  = w1al + 256 * 256;
  ushort* w1bl  = w1bh + 256 * 256;
  float*  T     = (float*)d_out;                 // T and final AF share d_out

  prep_weights<<<256, 256, 0, stream>>>(W_U2, W_U1, w2h, w2l, w1ah, w1al, w1bh, w1bl);
  embed_gemm<<<dim3(Mrows / 64, Hd / 64), 256, 0, stream>>>(input_atom, W_atom, AFhi, AFlo);

  for (int d = 0; d < 3; ++d) {
    // T = AF @ W2a :  AFhi*W2h + AFlo*W2h + AFhi*W2l
    SegPtrs st;
    st.a[0] = AFhi; st.a[1] = AFlo; st.a[2] = AFhi; st.a[3] = AFhi; st.a[4] = AFhi;
    st.b[0] = w2h;  st.b[1] = w2h;  st.b[2] = w2l;  st.b[3] = w2h;  st.b[4] = w2h;
    gemm_mfma<3, false, false><<<dim3(Mrows / 128, 2), 256, 0, stream>>>(st, nullptr, T);

    nei_kernel<<<Mrows / 8, 256, 0, stream>>>(T, input_bond, atom_graph, bond_graph,
                                              num_nbs, W_U2, b_U2, NEIbf);

    // AF' = relu(AF@W1a + NEI@W1b + b1):
    //   AFhi*W1ah + AFlo*W1ah + AFhi*W1al + NEI*W1bh + NEI*W1bl
    SegPtrs su;
    su.a[0] = AFhi; su.a[1] = AFlo; su.a[2] = AFhi; su.a[3] = NEIbf; su.a[4] = NEIbf;
    su.b[0] = w1ah; su.b[1] = w1ah; su.b[2] = w1al; su.b[3] = w1bh;  su.b[4] = w1bl;
    gemm_mfma<5, true, true><<<dim3(Mrows / 128, 2), 256, 0, stream>>>(su, b_U1, (float*)d_out);

    if (d < 2)
      split_convert<<<(int)(MH / 4 / 256), 256, 0, stream>>>((const float*)d_out, AFhi, AFlo);
  }
  // d_out holds the final atom_features (fp32).
}

// Round 3
// 323.011 us; speedup vs baseline: 2.5847x; 1.2209x over previous
//
#include <hip/hip_runtime.h>

// Problem constants (WLN_Edit): B=64, N=512, NB=600, A=89, E=5, H=256, MAX_NB=10, DEPTH=3
constexpr int Bb   = 64;
constexpr int Nn   = 512;
constexpr int NBb  = 600;
constexpr int Ad   = 89;
constexpr int Ed   = 5;
constexpr int Hd   = 256;
constexpr int MNB  = 10;
constexpr int Mrows = Bb * Nn;   // 32768
constexpr int Kpad  = 96;        // input_atom K padded to multiple of 32

typedef __bf16 bf16x8 __attribute__((ext_vector_type(8)));
typedef float  f32x4  __attribute__((ext_vector_type(4)));

typedef __attribute__((address_space(1))) const void gvoid_t;
typedef __attribute__((address_space(3))) void lvoid_t;

__device__ inline ushort bf_rne(float x) {
  unsigned u = __float_as_uint(x);
  unsigned r = (u + 0x7fffu + ((u >> 16) & 1u)) >> 16;
  return (ushort)r;
}
__device__ inline float bf_f(ushort h) { return __uint_as_float(((unsigned)h) << 16); }

// ---------------------------------------------------------------------------
// Weight prep: split fp32 weights into hi/lo bf16, TRANSPOSED to [n][k].
// ---------------------------------------------------------------------------
__global__ __launch_bounds__(256)
void prep_weights(const float* __restrict__ W_U2, const float* __restrict__ W_U1,
                  ushort* __restrict__ w2h, ushort* __restrict__ w2l,
                  ushort* __restrict__ w1ah, ushort* __restrict__ w1al,
                  ushort* __restrict__ w1bh, ushort* __restrict__ w1bl) {
  const int n = blockIdx.x;    // transposed row: 0..255
  const int k = threadIdx.x;   // 0..255
  const size_t o = (size_t)n * 256 + k;
  float v; ushort h;
  v = W_U2[(size_t)k * Hd + n];           h = bf_rne(v); w2h[o]  = h; w2l[o]  = bf_rne(v - bf_f(h));
  v = W_U1[(size_t)k * Hd + n];           h = bf_rne(v); w1ah[o] = h; w1al[o] = bf_rne(v - bf_f(h));
  v = W_U1[(size_t)(k + 256) * Hd + n];   h = bf_rne(v); w1bh[o] = h; w1bl[o] = bf_rne(v - bf_f(h));
}

// W_atom [89,256] -> hi/lo bf16 transposed+padded [256][96]
__global__ __launch_bounds__(128)
void prep_watom(const float* __restrict__ W, ushort* __restrict__ wh,
                ushort* __restrict__ wl) {
  const int n = blockIdx.x;
  const int k = threadIdx.x;
  if (k >= Kpad) return;
  const float v = (k < Ad) ? W[(size_t)k * Hd + n] : 0.f;
  const ushort h = bf_rne(v);
  wh[(size_t)n * Kpad + k] = h;
  wl[(size_t)n * Kpad + k] = bf_rne(v - bf_f(h));
}

// input_atom [32768,89] fp32 -> hi/lo bf16 padded [32768][96]
__global__ __launch_bounds__(192)
void conv_atom(const float* __restrict__ A, ushort* __restrict__ hi,
               ushort* __restrict__ lo) {
  const int tid = threadIdx.x;
  const int r2 = (tid >= Kpad) ? 1 : 0;
  const int c = tid - r2 * Kpad;
  const int m = blockIdx.x * 2 + r2;
  const float v = (c < Ad) ? A[(size_t)m * Ad + c] : 0.f;
  const ushort h = bf_rne(v);
  hi[(size_t)m * Kpad + c] = h;
  lo[(size_t)m * Kpad + c] = bf_rne(v - bf_f(h));
}

// ---------------------------------------------------------------------------
// MFMA GEMM: C[32768,256] = op( sum_seg A_seg(M x kdepth) @ B_seg(kdepth x 256) )
// A segs: bf16 [m][k] stride kdepth. B segs: bf16 TRANSPOSED [n][k] stride kdepth.
// 128x128 tile, BK=32, 4 waves, mfma_f32_16x16x32_bf16, global_load_lds(16B).
// OUTMODE: 0 = fp32 to Cf; 1 = split hi/lo bf16 to Chi/Clo; 2 = single bf16 to Chi.
// ---------------------------------------------------------------------------
struct SegPtrs { const ushort* a[5]; const ushort* b[5]; };

template<int NSEG, int OUTMODE, bool RELU, bool BIAS>
__global__ __launch_bounds__(256)
void gemm_mfma(SegPtrs segs, int kdepth, const float* __restrict__ bias,
               float* __restrict__ Cf, ushort* __restrict__ Chi,
               ushort* __restrict__ Clo) {
  __shared__ ushort As[128 * 32];
  __shared__ ushort Bs[128 * 32];
  const int tid  = threadIdx.x;
  const int lane = tid & 63;
  const int w    = tid >> 6;
  const int wr   = w >> 1, wc = w & 1;
  const int m0   = blockIdx.x * 128;
  const int n0   = blockIdx.y * 128;
  const int arow = tid >> 2;          // 0..63 tile row per staging round
  const int acol = (tid & 3) * 8;     // element col base within BK=32
  const int fr   = lane & 15;
  const int fq   = lane >> 4;
  const int nk   = kdepth >> 5;

  f32x4 acc[4][4] = {};

#pragma unroll
  for (int seg = 0; seg < NSEG; ++seg) {
    const ushort* __restrict__ Aseg = segs.a[seg];
    const ushort* __restrict__ Bseg = segs.b[seg];
    for (int k8 = 0; k8 < nk; ++k8) {
      const int kk = k8 * 32;
#pragma unroll
      for (int i = 0; i < 2; ++i) {
        const ushort* ga = Aseg + (size_t)(m0 + arow + 64 * i) * kdepth + kk + acol;
        const ushort* gb = Bseg + (size_t)(n0 + arow + 64 * i) * kdepth + kk + acol;
        __builtin_amdgcn_global_load_lds((gvoid_t*)ga,
            (lvoid_t*)(As + i * 2048 + w * 512), 16, 0, 0);
        __builtin_amdgcn_global_load_lds((gvoid_t*)gb,
            (lvoid_t*)(Bs + i * 2048 + w * 512), 16, 0, 0);
      }
      __syncthreads();

      bf16x8 bfr[4];
#pragma unroll
      for (int nf = 0; nf < 4; ++nf)
        bfr[nf] = *reinterpret_cast<const bf16x8*>(&Bs[(wc * 64 + nf * 16 + fr) * 32 + fq * 8]);
#pragma unroll
      for (int mf = 0; mf < 4; ++mf) {
        bf16x8 af = *reinterpret_cast<const bf16x8*>(&As[(wr * 64 + mf * 16 + fr) * 32 + fq * 8]);
#pragma unroll
        for (int nf = 0; nf < 4; ++nf)
          acc[mf][nf] = __builtin_amdgcn_mfma_f32_16x16x32_bf16(af, bfr[nf], acc[mf][nf], 0, 0, 0);
      }
      __syncthreads();
    }
  }

  // epilogue: C/D layout col=lane&15, row=(lane>>4)*4+reg  [verified m89]
#pragma unroll
  for (int mf = 0; mf < 4; ++mf) {
#pragma unroll
    for (int nf = 0; nf < 4; ++nf) {
      const int col = n0 + wc * 64 + nf * 16 + fr;
      float bv = 0.f;
      if constexpr (BIAS) bv = bias[col];
#pragma unroll
      for (int r = 0; r < 4; ++r) {
        const int row = m0 + wr * 64 + mf * 16 + fq * 4 + r;
        float v = acc[mf][nf][r] + bv;
        if constexpr (RELU) v = fmaxf(v, 0.f);
        const size_t o = (size_t)row * Hd + col;
        if constexpr (OUTMODE == 0) {
          Cf[o] = v;
        } else if constexpr (OUTMODE == 2) {
          Chi[o] = bf_rne(v);
        } else {
          const ushort h = bf_rne(v);
          Chi[o] = h;
          Clo[o] = bf_rne(v - bf_f(h));
        }
      }
    }
  }
}

// ---------------------------------------------------------------------------
// Fused neighbor kernel (bf16 T): NEI[m,h] = sum_{k<nn} relu(T[gth] + bond·W + b)
// Thread owns an h-PAIR (ushort2 T loads). All 10 indices loaded up front;
// T loads issued unconditionally with clamped indices (branch-free, in flight).
// ---------------------------------------------------------------------------
__global__ __launch_bounds__(256)
void nei_kernel(const ushort* __restrict__ T, const float* __restrict__ input_bond,
                const int* __restrict__ atom_graph, const int* __restrict__ bond_graph,
                const int* __restrict__ num_nbs,
                const float* __restrict__ W_U2, const float* __restrict__ b_U2,
                ushort* __restrict__ NEI) {
  const int tid = threadIdx.x;
  const int hp = tid & 127;           // h-pair index
  const int rp = tid >> 7;            // row parity within pair of rows
  int bid = blockIdx.x;
  bid = (bid & 7) * (gridDim.x >> 3) + (bid >> 3);   // XCD chunk swizzle (8192%8==0)
  const int m0 = bid * 8;
  const int h0 = hp * 2;

  float wb0[Ed], wb1[Ed];
#pragma unroll
  for (int e = 0; e < Ed; ++e) {
    wb0[e] = W_U2[(size_t)(Hd + e) * Hd + h0];
    wb1[e] = W_U2[(size_t)(Hd + e) * Hd + h0 + 1];
  }
  const float b20 = b_U2[h0], b21 = b_U2[h0 + 1];

#pragma unroll
  for (int j = 0; j < 4; ++j) {
    const int m = m0 + j * 2 + rp;
    const int b = m >> 9;
    const int nn = num_nbs[m];
    int ai[MNB], bi[MNB];
#pragma unroll
    for (int k = 0; k < MNB; ++k) {
      ai[k] = atom_graph[((size_t)m * MNB + k) * 2 + 1];
      bi[k] = bond_graph[((size_t)m * MNB + k) * 2 + 1];
    }
#pragma unroll
    for (int k = 1; k < MNB; ++k) {      // clamp (k=0 always valid: nn>=1)
      ai[k] = (k < nn) ? ai[k] : ai[0];
      bi[k] = (k < nn) ? bi[k] : bi[0];
    }
    unsigned tv[MNB];
#pragma unroll
    for (int k = 0; k < MNB; ++k)
      tv[k] = *reinterpret_cast<const unsigned*>(
          &T[(((size_t)b << 9) + (size_t)ai[k]) * Hd + h0]);

    float acc0 = 0.f, acc1 = 0.f;
#pragma unroll
    for (int k = 0; k < MNB; ++k) {
      const float* bp = input_bond + ((size_t)b * NBb + bi[k]) * Ed;
      float d0 = b20, d1 = b21;
#pragma unroll
      for (int e = 0; e < Ed; ++e) {
        const float f = bp[e];
        d0 = fmaf(f, wb0[e], d0);
        d1 = fmaf(f, wb1[e], d1);
      }
      const float v0 = bf_f((ushort)(tv[k] & 0xffffu)) + d0;
      const float v1 = bf_f((ushort)(tv[k] >> 16)) + d1;
      if (k < nn) { acc0 += fmaxf(v0, 0.f); acc1 += fmaxf(v1, 0.f); }
    }
    const unsigned o = (unsigned)bf_rne(acc0) | ((unsigned)bf_rne(acc1) << 16);
    *reinterpret_cast<unsigned*>(&NEI[(size_t)m * Hd + h0]) = o;
  }
}

extern "C" void kernel_launch(void* const* d_in, const int* in_sizes, int n_in,
                              void* d_out, int out_size, void* d_ws, size_t ws_size,
                              hipStream_t stream) {
  const float* input_atom = (const float*)d_in[0];
  const float* input_bond = (const float*)d_in[1];
  const int*   atom_graph = (const int*)d_in[2];
  const int*   bond_graph = (const int*)d_in[3];
  const int*   num_nbs    = (const int*)d_in[4];
  const float* W_atom     = (const float*)d_in[5];
  const float* W_U2       = (const float*)d_in[6];
  const float* b_U2       = (const float*)d_in[7];
  const float* W_U1       = (const float*)d_in[8];
  const float* b_U1       = (const float*)d_in[9];

  const size_t MH = (size_t)Mrows * Hd;          // 8,388,608
  // ws layout (ushorts): AFhi, AFlo, NEI, Apad hi/lo, weight panels  (~63.8 MB)
  ushort* wAFhi = (ushort*)d_ws;
  ushort* wAFlo = wAFhi + MH;
  ushort* NEIbf = wAFlo + MH;
  ushort* Apadh = NEIbf + MH;
  ushort* Apadl = Apadh + (size_t)Mrows * Kpad;
  ushort* w2h   = Apadl + (size_t)Mrows * Kpad;
  ushort* w2l   = w2h  + 256 * 256;
  ushort* w1ah  = w2l  + 256 * 256;
  ushort* w1al  = w1ah + 256 * 256;
  ushort* w1bh  = w1al + 256 * 256;
  ushort* w1bl  = w1bh + 256 * 256;
  ushort* wah   = w1bl + 256 * 256;
  ushort* wal   = wah  + 256 * Kpad;

  // AF homes ping-pong: home0 = ws, home1 = d_out (2 x 16MB halves).
  ushort* hiH[2] = { wAFhi, (ushort*)d_out };
  ushort* loH[2] = { wAFlo, (ushort*)d_out + MH };

  const dim3 blk(256);
  const dim3 gG(Mrows / 128, 2);

  prep_weights<<<256, 256, 0, stream>>>(W_U2, W_U1, w2h, w2l, w1ah, w1al, w1bh, w1bl);
  prep_watom<<<256, 128, 0, stream>>>(W_atom, wah, wal);
  conv_atom<<<Mrows / 2, 192, 0, stream>>>(input_atom, Apadh, Apadl);

  // embed: AF0 = input_atom @ W_atom  (split-bf16 MFMA, K=96) -> home0
  {
    SegPtrs se{};
    se.a[0] = Apadh; se.a[1] = Apadl; se.a[2] = Apadh;
    se.b[0] = wah;   se.b[1] = wah;   se.b[2] = wal;
    gemm_mfma<3, 1, false, false><<<gG, blk, 0, stream>>>(se, Kpad, nullptr,
                                                          nullptr, wAFhi, wAFlo);
  }

  for (int d = 0; d < 3; ++d) {
    const int cur = d & 1;               // AF home this depth: 0,1,0
    ushort* Tbf = hiH[1 - cur];          // T lives in the OTHER home's hi region (dead)

    // T = AF @ W2a (3 split segs) -> bf16
    SegPtrs st{};
    st.a[0] = hiH[cur]; st.a[1] = loH[cur]; st.a[2] = hiH[cur];
    st.b[0] = w2h;      st.b[1] = w2h;      st.b[2] = w2l;
    gemm_mfma<3, 2, false, false><<<gG, blk, 0, stream>>>(st, Hd, nullptr,
                                                          nullptr, Tbf, nullptr);

    nei_kernel<<<Mrows / 8, blk, 0, stream>>>(Tbf, input_bond, atom_graph,
                                              bond_graph, num_nbs, W_U2, b_U2, NEIbf);

    // AF' = relu(AF@W1a + NEI@W1b + b1)  (5 segs)
    SegPtrs su{};
    su.a[0] = hiH[cur]; su.a[1] = loH[cur]; su.a[2] = hiH[cur]; su.a[3] = NEIbf; su.a[4] = NEIbf;
    su.b[0] = w1ah;     su.b[1] = w1ah;     su.b[2] = w1al;     su.b[3] = w1bh;  su.b[4] = w1bl;
    if (d < 2) {
      gemm_mfma<5, 1, true, true><<<gG, blk, 0, stream>>>(su, Hd, b_U1,
                                                          nullptr, hiH[1 - cur], loH[1 - cur]);
    } else {
      gemm_mfma<5, 0, true, true><<<gG, blk, 0, stream>>>(su, Hd, b_U1,
                                                          (float*)d_out, nullptr, nullptr);
    }
  }
  // d_out holds the final atom_features (fp32).
}

// Round 4
// 257.590 us; speedup vs baseline: 3.2412x; 1.2540x over previous
//
#include <hip/hip_runtime.h>

// Problem constants (WLN_Edit): B=64, N=512, NB=600, A=89, E=5, H=256, MAX_NB=10, DEPTH=3
constexpr int Bb   = 64;
constexpr int Nn   = 512;
constexpr int NBb  = 600;
constexpr int Ad   = 89;
constexpr int Ed   = 5;
constexpr int Hd   = 256;
constexpr int MNB  = 10;
constexpr int Mrows  = Bb * Nn;    // 32768
constexpr int NBrows = Bb * NBb;   // 38400
constexpr int Kpad   = 96;

typedef __bf16 bf16x8 __attribute__((ext_vector_type(8)));
typedef float  f32x4  __attribute__((ext_vector_type(4)));

typedef __attribute__((address_space(1))) const void gvoid_t;
typedef __attribute__((address_space(3))) void lvoid_t;

__device__ inline ushort bf_rne(float x) {
  unsigned u = __float_as_uint(x);
  unsigned r = (u + 0x7fffu + ((u >> 16) & 1u)) >> 16;
  return (ushort)r;
}
__device__ inline float bf_f(ushort h) { return __uint_as_float(((unsigned)h) << 16); }

// ---------------------------------------------------------------------------
// Weight prep: split fp32 weights into bf16 panels, TRANSPOSED to [n][k].
// Kept panels: w2h (W2a hi), w1ah/w1al (W1a hi+lo), w1bh (W1b hi).
// ---------------------------------------------------------------------------
__global__ __launch_bounds__(256)
void prep_weights(const float* __restrict__ W_U2, const float* __restrict__ W_U1,
                  ushort* __restrict__ w2h, ushort* __restrict__ w1ah,
                  ushort* __restrict__ w1al, ushort* __restrict__ w1bh) {
  const int n = blockIdx.x;    // transposed row 0..255
  const int k = threadIdx.x;   // 0..255
  const size_t o = (size_t)n * 256 + k;
  float v; ushort h;
  v = W_U2[(size_t)k * Hd + n];           w2h[o]  = bf_rne(v);
  v = W_U1[(size_t)k * Hd + n];           h = bf_rne(v); w1ah[o] = h; w1al[o] = bf_rne(v - bf_f(h));
  v = W_U1[(size_t)(k + 256) * Hd + n];   w1bh[o] = bf_rne(v);
}

// W_atom [89,256] -> hi/lo bf16 transposed+padded [256][96]
__global__ __launch_bounds__(128)
void prep_watom(const float* __restrict__ W, ushort* __restrict__ wh,
                ushort* __restrict__ wl) {
  const int n = blockIdx.x;
  const int k = threadIdx.x;
  if (k >= Kpad) return;
  const float v = (k < Ad) ? W[(size_t)k * Hd + n] : 0.f;
  const ushort h = bf_rne(v);
  wh[(size_t)n * Kpad + k] = h;
  wl[(size_t)n * Kpad + k] = bf_rne(v - bf_f(h));
}

// input_atom [32768,89] fp32 -> hi/lo bf16 padded [32768][96]
__global__ __launch_bounds__(192)
void conv_atom(const float* __restrict__ A, ushort* __restrict__ hi,
               ushort* __restrict__ lo) {
  const int tid = threadIdx.x;
  const int r2 = (tid >= Kpad) ? 1 : 0;
  const int c = tid - r2 * Kpad;
  const int m = blockIdx.x * 2 + r2;
  const float v = (c < Ad) ? A[(size_t)m * Ad + c] : 0.f;
  const ushort h = bf_rne(v);
  hi[(size_t)m * Kpad + c] = h;
  lo[(size_t)m * Kpad + c] = bf_rne(v - bf_f(h));
}

// ---------------------------------------------------------------------------
// Z precompute (depth-invariant): Z[b,i,h] = input_bond[b,i,:]@W_U2[256:,h] + b_U2[h]
// ---------------------------------------------------------------------------
__global__ __launch_bounds__(256)
void zprep(const float* __restrict__ input_bond, const float* __restrict__ W_U2,
           const float* __restrict__ b_U2, ushort* __restrict__ Z) {
  const int h = threadIdx.x;
  const int r0 = blockIdx.x * 8;
  float w[Ed];
#pragma unroll
  for (int e = 0; e < Ed; ++e) w[e] = W_U2[(size_t)(Hd + e) * Hd + h];
  const float b2 = b_U2[h];
#pragma unroll
  for (int j = 0; j < 8; ++j) {
    const int r = r0 + j;
    const float* bp = input_bond + (size_t)r * Ed;
    float d = b2;
#pragma unroll
    for (int e = 0; e < Ed; ++e) d = fmaf(bp[e], w[e], d);
    Z[(size_t)r * Hd + h] = bf_rne(d);
  }
}

// ---------------------------------------------------------------------------
// MFMA GEMM, double-buffered 2-phase: C = op( sum_seg A_seg @ B_seg^T )
// A segs: bf16 [m][KD]; B segs: bf16 transposed [n][KD]. 128x128 tile, BK=32,
// 4 waves, mfma_f32_16x16x32_bf16, global_load_lds(16B), 1 barrier/K-step.
// OUTMODE: 0 = fp32; 1 = split hi/lo bf16; 2 = single bf16.
// ---------------------------------------------------------------------------
struct SegPtrs { const ushort* a[4]; const ushort* b[4]; };

template<int NSEG, int KD, int OUTMODE, bool RELU, bool BIAS>
__global__ __launch_bounds__(256)
void gemm_mfma(SegPtrs segs, const float* __restrict__ bias,
               float* __restrict__ Cf, ushort* __restrict__ Chi,
               ushort* __restrict__ Clo) {
  constexpr int NK = KD / 32;
  constexpr int TS = NSEG * NK;
  __shared__ ushort As[2][4096];
  __shared__ ushort Bs[2][4096];
  const int tid  = threadIdx.x;
  const int lane = tid & 63;
  const int w    = tid >> 6;
  const int wr   = w >> 1, wc = w & 1;
  const int m0   = blockIdx.x * 128;
  const int n0   = blockIdx.y * 128;
  const int arow = tid >> 2;
  const int acol = (tid & 3) * 8;
  const int fr   = lane & 15;
  const int fq   = lane >> 4;

  f32x4 acc[4][4] = {};

  auto stage = [&](const ushort* Aseg, const ushort* Bseg, int kk, int db) {
#pragma unroll
    for (int i = 0; i < 2; ++i) {
      const ushort* ga = Aseg + (size_t)(m0 + arow + 64 * i) * KD + kk + acol;
      const ushort* gb = Bseg + (size_t)(n0 + arow + 64 * i) * KD + kk + acol;
      __builtin_amdgcn_global_load_lds((gvoid_t*)ga,
          (lvoid_t*)(&As[db][i * 2048 + w * 512]), 16, 0, 0);
      __builtin_amdgcn_global_load_lds((gvoid_t*)gb,
          (lvoid_t*)(&Bs[db][i * 2048 + w * 512]), 16, 0, 0);
    }
  };

  stage(segs.a[0], segs.b[0], 0, 0);
  __syncthreads();

#pragma unroll
  for (int ts = 0; ts < TS; ++ts) {
    const int db = ts & 1;
    if (ts + 1 < TS) {                       // prefetch next K-step into buf^1
      const int s2 = (ts + 1) / NK;
      const int k2 = (ts + 1) % NK;
      stage(segs.a[s2], segs.b[s2], k2 * 32, db ^ 1);
    }
    bf16x8 bfr[4];
#pragma unroll
    for (int nf = 0; nf < 4; ++nf)
      bfr[nf] = *reinterpret_cast<const bf16x8*>(&Bs[db][(wc * 64 + nf * 16 + fr) * 32 + fq * 8]);
#pragma unroll
    for (int mf = 0; mf < 4; ++mf) {
      bf16x8 af = *reinterpret_cast<const bf16x8*>(&As[db][(wr * 64 + mf * 16 + fr) * 32 + fq * 8]);
#pragma unroll
      for (int nf = 0; nf < 4; ++nf)
        acc[mf][nf] = __builtin_amdgcn_mfma_f32_16x16x32_bf16(af, bfr[nf], acc[mf][nf], 0, 0, 0);
    }
    __syncthreads();   // drains this step's stage (vmcnt) + all reads of buf db
  }

  // epilogue: C/D layout col=lane&15, row=(lane>>4)*4+reg  [verified m89]
#pragma unroll
  for (int mf = 0; mf < 4; ++mf) {
#pragma unroll
    for (int nf = 0; nf < 4; ++nf) {
      const int col = n0 + wc * 64 + nf * 16 + fr;
      float bv = 0.f;
      if constexpr (BIAS) bv = bias[col];
#pragma unroll
      for (int r = 0; r < 4; ++r) {
        const int row = m0 + wr * 64 + mf * 16 + fq * 4 + r;
        float v = acc[mf][nf][r] + bv;
        if constexpr (RELU) v = fmaxf(v, 0.f);
        const size_t o = (size_t)row * Hd + col;
        if constexpr (OUTMODE == 0) {
          Cf[o] = v;
        } else if constexpr (OUTMODE == 2) {
          Chi[o] = bf_rne(v);
        } else {
          const ushort h = bf_rne(v);
          Chi[o] = h;
          Clo[o] = bf_rne(v - bf_f(h));
        }
      }
    }
  }
}

// ---------------------------------------------------------------------------
// nei with precomputed Z: NEI[m,h] = sum_{k<nn} relu(T[ai[k]] + Z[bi[k]])
// Thread owns an h-QUAD (uint2 loads). All gathers issued up front.
// ---------------------------------------------------------------------------
__global__ __launch_bounds__(256)
void nei_z(const ushort* __restrict__ T, const ushort* __restrict__ Z,
           const int* __restrict__ atom_graph, const int* __restrict__ bond_graph,
           const int* __restrict__ num_nbs, ushort* __restrict__ NEI) {
  const int tid = threadIdx.x;
  const int hq = tid & 63;
  const int rp = tid >> 6;
  int bid = blockIdx.x;
  bid = (bid & 7) * (gridDim.x >> 3) + (bid >> 3);   // XCD swizzle (4096%8==0)
  const int m0 = bid * 8;
  const int h0 = hq * 4;

#pragma unroll
  for (int j = 0; j < 2; ++j) {
    const int m = m0 + j * 4 + rp;
    const int b = m >> 9;
    const int nn = num_nbs[m];
    int ai[MNB], bi[MNB];
#pragma unroll
    for (int k = 0; k < MNB; ++k) {
      ai[k] = atom_graph[((size_t)m * MNB + k) * 2 + 1];
      bi[k] = bond_graph[((size_t)m * MNB + k) * 2 + 1];
    }
#pragma unroll
    for (int k = 1; k < MNB; ++k) {          // clamp (nn>=1 always)
      ai[k] = (k < nn) ? ai[k] : ai[0];
      bi[k] = (k < nn) ? bi[k] : bi[0];
    }
    uint2 tv[MNB], zv[MNB];
#pragma unroll
    for (int k = 0; k < MNB; ++k) {
      tv[k] = *reinterpret_cast<const uint2*>(&T[(((size_t)b << 9) + ai[k]) * Hd + h0]);
      zv[k] = *reinterpret_cast<const uint2*>(&Z[((size_t)b * NBb + bi[k]) * Hd + h0]);
    }
    float a0 = 0.f, a1 = 0.f, a2 = 0.f, a3 = 0.f;
#pragma unroll
    for (int k = 0; k < MNB; ++k) {
      if (k < nn) {   // wave-uniform branch
        const float t0 = __uint_as_float(tv[k].x << 16);
        const float t1 = __uint_as_float(tv[k].x & 0xffff0000u);
        const float t2 = __uint_as_float(tv[k].y << 16);
        const float t3 = __uint_as_float(tv[k].y & 0xffff0000u);
        const float z0 = __uint_as_float(zv[k].x << 16);
        const float z1 = __uint_as_float(zv[k].x & 0xffff0000u);
        const float z2 = __uint_as_float(zv[k].y << 16);
        const float z3 = __uint_as_float(zv[k].y & 0xffff0000u);
        a0 += fmaxf(t0 + z0, 0.f);
        a1 += fmaxf(t1 + z1, 0.f);
        a2 += fmaxf(t2 + z2, 0.f);
        a3 += fmaxf(t3 + z3, 0.f);
      }
    }
    uint2 o;
    o.x = (unsigned)bf_rne(a0) | ((unsigned)bf_rne(a1) << 16);
    o.y = (unsigned)bf_rne(a2) | ((unsigned)bf_rne(a3) << 16);
    *reinterpret_cast<uint2*>(&NEI[(size_t)m * Hd + h0]) = o;
  }
}

// ---------------------------------------------------------------------------
// Fallback nei (no Z buffer; recomputes bond dots) — used if ws too small.
// ---------------------------------------------------------------------------
__global__ __launch_bounds__(256)
void nei_fb(const ushort* __restrict__ T, const float* __restrict__ input_bond,
            const int* __restrict__ atom_graph, const int* __restrict__ bond_graph,
            const int* __restrict__ num_nbs,
            const float* __restrict__ W_U2, const float* __restrict__ b_U2,
            ushort* __restrict__ NEI) {
  const int tid = threadIdx.x;
  const int hp = tid & 127;
  const int rp = tid >> 7;
  int bid = blockIdx.x;
  bid = (bid & 7) * (gridDim.x >> 3) + (bid >> 3);
  const int m0 = bid * 8;
  const int h0 = hp * 2;

  float wb0[Ed], wb1[Ed];
#pragma unroll
  for (int e = 0; e < Ed; ++e) {
    wb0[e] = W_U2[(size_t)(Hd + e) * Hd + h0];
    wb1[e] = W_U2[(size_t)(Hd + e) * Hd + h0 + 1];
  }
  const float b20 = b_U2[h0], b21 = b_U2[h0 + 1];

#pragma unroll
  for (int j = 0; j < 4; ++j) {
    const int m = m0 + j * 2 + rp;
    const int b = m >> 9;
    const int nn = num_nbs[m];
    int ai[MNB], bi[MNB];
#pragma unroll
    for (int k = 0; k < MNB; ++k) {
      ai[k] = atom_graph[((size_t)m * MNB + k) * 2 + 1];
      bi[k] = bond_graph[((size_t)m * MNB + k) * 2 + 1];
    }
#pragma unroll
    for (int k = 1; k < MNB; ++k) {
      ai[k] = (k < nn) ? ai[k] : ai[0];
      bi[k] = (k < nn) ? bi[k] : bi[0];
    }
    unsigned tv[MNB];
#pragma unroll
    for (int k = 0; k < MNB; ++k)
      tv[k] = *reinterpret_cast<const unsigned*>(
          &T[(((size_t)b << 9) + (size_t)ai[k]) * Hd + h0]);

    float acc0 = 0.f, acc1 = 0.f;
#pragma unroll
    for (int k = 0; k < MNB; ++k) {
      const float* bp = input_bond + ((size_t)b * NBb + bi[k]) * Ed;
      float d0 = b20, d1 = b21;
#pragma unroll
      for (int e = 0; e < Ed; ++e) {
        const float f = bp[e];
        d0 = fmaf(f, wb0[e], d0);
        d1 = fmaf(f, wb1[e], d1);
      }
      const float v0 = bf_f((ushort)(tv[k] & 0xffffu)) + d0;
      const float v1 = bf_f((ushort)(tv[k] >> 16)) + d1;
      if (k < nn) { acc0 += fmaxf(v0, 0.f); acc1 += fmaxf(v1, 0.f); }
    }
    const unsigned o = (unsigned)bf_rne(acc0) | ((unsigned)bf_rne(acc1) << 16);
    *reinterpret_cast<unsigned*>(&NEI[(size_t)m * Hd + h0]) = o;
  }
}

extern "C" void kernel_launch(void* const* d_in, const int* in_sizes, int n_in,
                              void* d_out, int out_size, void* d_ws, size_t ws_size,
                              hipStream_t stream) {
  const float* input_atom = (const float*)d_in[0];
  const float* input_bond = (const float*)d_in[1];
  const int*   atom_graph = (const int*)d_in[2];
  const int*   bond_graph = (const int*)d_in[3];
  const int*   num_nbs    = (const int*)d_in[4];
  const float* W_atom     = (const float*)d_in[5];
  const float* W_U2       = (const float*)d_in[6];
  const float* b_U2       = (const float*)d_in[7];
  const float* W_U1       = (const float*)d_in[8];
  const float* b_U1       = (const float*)d_in[9];

  const size_t SL = (size_t)Mrows * Hd;          // 8,388,608 ushorts = 16.78 MB
  ushort* AFhi0 = (ushort*)d_ws;
  ushort* AFlo0 = AFhi0 + SL;
  ushort* NEIbf = AFlo0 + SL;
  ushort* w2h   = NEIbf + SL;
  ushort* w1ah  = w2h  + 256 * 256;
  ushort* w1al  = w1ah + 256 * 256;
  ushort* w1bh  = w1al + 256 * 256;
  ushort* wah   = w1bh + 256 * 256;
  ushort* wal   = wah  + 256 * Kpad;
  ushort* apz   = wal  + 256 * Kpad;             // Apad ∪ Z union region
  ushort* Apadh = apz;
  ushort* Apadl = apz + (size_t)Mrows * Kpad;
  ushort* Zbuf  = apz;                           // overwrites Apad after embed

  const size_t need_z = ((size_t)(apz - AFhi0) + (size_t)NBrows * Hd) * sizeof(ushort);
  const bool useZ = (ws_size >= need_z);

  // AF homes ping-pong: home0 = ws, home1 = d_out halves.
  ushort* hiH[2] = { AFhi0, (ushort*)d_out };
  ushort* loH[2] = { AFlo0, (ushort*)d_out + SL };

  const dim3 blk(256);
  const dim3 gG(Mrows / 128, 2);

  prep_weights<<<256, 256, 0, stream>>>(W_U2, W_U1, w2h, w1ah, w1al, w1bh);
  prep_watom<<<256, 128, 0, stream>>>(W_atom, wah, wal);
  conv_atom<<<Mrows / 2, 192, 0, stream>>>(input_atom, Apadh, Apadl);

  // embed: AF0 = input_atom @ W_atom (3 segs, K=96) -> home0 (hi/lo)
  {
    SegPtrs se{};
    se.a[0] = Apadh; se.a[1] = Apadl; se.a[2] = Apadh;
    se.b[0] = wah;   se.b[1] = wah;   se.b[2] = wal;
    gemm_mfma<3, Kpad, 1, false, false><<<gG, blk, 0, stream>>>(se, nullptr,
                                                                nullptr, AFhi0, AFlo0);
  }
  if (useZ)   // Z overwrites Apad region — must follow embed
    zprep<<<NBrows / 8, 256, 0, stream>>>(input_bond, W_U2, b_U2, Zbuf);

  for (int d = 0; d < 3; ++d) {
    const int cur = d & 1;
    ushort* Tbf = hiH[1 - cur];          // T lives in the other home's hi region

    // T = AF @ W2a (2 segs: AFhi@W2h + AFlo@W2h) -> bf16
    SegPtrs st{};
    st.a[0] = hiH[cur]; st.a[1] = loH[cur];
    st.b[0] = w2h;      st.b[1] = w2h;
    gemm_mfma<2, Hd, 2, false, false><<<gG, blk, 0, stream>>>(st, nullptr,
                                                              nullptr, Tbf, nullptr);

    if (useZ)
      nei_z<<<Mrows / 8, blk, 0, stream>>>(Tbf, Zbuf, atom_graph, bond_graph,
                                           num_nbs, NEIbf);
    else
      nei_fb<<<Mrows / 8, blk, 0, stream>>>(Tbf, input_bond, atom_graph, bond_graph,
                                            num_nbs, W_U2, b_U2, NEIbf);

    // AF' = relu(AF@W1a + NEI@W1b + b1): 4 segs
    SegPtrs su{};
    su.a[0] = hiH[cur]; su.a[1] = loH[cur]; su.a[2] = hiH[cur]; su.a[3] = NEIbf;
    su.b[0] = w1ah;     su.b[1] = w1ah;     su.b[2] = w1al;     su.b[3] = w1bh;
    if (d < 2) {
      gemm_mfma<4, Hd, 1, true, true><<<gG, blk, 0, stream>>>(su, b_U1,
                                                              nullptr, hiH[1 - cur], loH[1 - cur]);
    } else {
      gemm_mfma<4, Hd, 0, true, true><<<gG, blk, 0, stream>>>(su, b_U1,
                                                              (float*)d_out, nullptr, nullptr);
    }
  }
  // d_out holds the final atom_features (fp32).
}

// Round 5
// 205.337 us; speedup vs baseline: 4.0659x; 1.2545x over previous
//
#include <hip/hip_runtime.h>

// Problem constants (WLN_Edit): B=64, N=512, NB=600, A=89, E=5, H=256, MAX_NB=10, DEPTH=3
constexpr int Bb   = 64;
constexpr int Nn   = 512;
constexpr int NBb  = 600;
constexpr int Ad   = 89;
constexpr int Ed   = 5;
constexpr int Hd   = 256;
constexpr int MNB  = 10;
constexpr int Mrows  = Bb * Nn;    // 32768
constexpr int NBrows = Bb * NBb;   // 38400
constexpr int Kpad   = 96;

typedef __bf16 bf16x8 __attribute__((ext_vector_type(8)));
typedef float  f32x4  __attribute__((ext_vector_type(4)));

typedef __attribute__((address_space(1))) const void gvoid_t;
typedef __attribute__((address_space(3))) void lvoid_t;

__device__ inline ushort bf_rne(float x) {
  unsigned u = __float_as_uint(x);
  unsigned r = (u + 0x7fffu + ((u >> 16) & 1u)) >> 16;
  return (ushort)r;
}
__device__ inline float bf_f(ushort h) { return __uint_as_float(((unsigned)h) << 16); }

// ---------------------------------------------------------------------------
// Weight prep: bf16 panels TRANSPOSED to [n][k]: w2h (W2a), w1ah (W1a), w1bh (W1b).
// ---------------------------------------------------------------------------
__global__ __launch_bounds__(256)
void prep_weights(const float* __restrict__ W_U2, const float* __restrict__ W_U1,
                  ushort* __restrict__ w2h, ushort* __restrict__ w1ah,
                  ushort* __restrict__ w1bh) {
  const int n = blockIdx.x;
  const int k = threadIdx.x;
  const size_t o = (size_t)n * 256 + k;
  w2h[o]  = bf_rne(W_U2[(size_t)k * Hd + n]);
  w1ah[o] = bf_rne(W_U1[(size_t)k * Hd + n]);
  w1bh[o] = bf_rne(W_U1[(size_t)(k + 256) * Hd + n]);
}

// W_atom [89,256] -> hi/lo bf16 transposed+padded [256][96]
__global__ __launch_bounds__(128)
void prep_watom(const float* __restrict__ W, ushort* __restrict__ wh,
                ushort* __restrict__ wl) {
  const int n = blockIdx.x;
  const int k = threadIdx.x;
  if (k >= Kpad) return;
  const float v = (k < Ad) ? W[(size_t)k * Hd + n] : 0.f;
  const ushort h = bf_rne(v);
  wh[(size_t)n * Kpad + k] = h;
  wl[(size_t)n * Kpad + k] = bf_rne(v - bf_f(h));
}

// input_atom [32768,89] fp32 -> hi/lo bf16 padded [32768][96]
__global__ __launch_bounds__(192)
void conv_atom(const float* __restrict__ A, ushort* __restrict__ hi,
               ushort* __restrict__ lo) {
  const int tid = threadIdx.x;
  const int r2 = (tid >= Kpad) ? 1 : 0;
  const int c = tid - r2 * Kpad;
  const int m = blockIdx.x * 2 + r2;
  const float v = (c < Ad) ? A[(size_t)m * Ad + c] : 0.f;
  const ushort h = bf_rne(v);
  hi[(size_t)m * Kpad + c] = h;
  lo[(size_t)m * Kpad + c] = bf_rne(v - bf_f(h));
}

// ---------------------------------------------------------------------------
// Z precompute (depth-invariant): Z[b,i,h] = input_bond[b,i,:]@W_U2[256:,h] + b_U2[h]
// ---------------------------------------------------------------------------
__global__ __launch_bounds__(256)
void zprep(const float* __restrict__ input_bond, const float* __restrict__ W_U2,
           const float* __restrict__ b_U2, ushort* __restrict__ Z) {
  const int h = threadIdx.x;
  const int r0 = blockIdx.x * 8;
  float w[Ed];
#pragma unroll
  for (int e = 0; e < Ed; ++e) w[e] = W_U2[(size_t)(Hd + e) * Hd + h];
  const float b2 = b_U2[h];
#pragma unroll
  for (int j = 0; j < 8; ++j) {
    const int r = r0 + j;
    const float* bp = input_bond + (size_t)r * Ed;
    float d = b2;
#pragma unroll
    for (int e = 0; e < Ed; ++e) d = fmaf(bp[e], w[e], d);
    Z[(size_t)r * Hd + h] = bf_rne(d);
  }
}

// ---------------------------------------------------------------------------
// MFMA GEMM, double-buffered 2-phase: C = op( sum_seg A_seg @ B_seg^T )
// A segs: bf16 [m][KD]; B segs: bf16 transposed [n][KD]. 128x128 tile, BK=32,
// 4 waves, mfma_f32_16x16x32_bf16, global_load_lds(16B), 1 barrier/K-step.
// OUTMODE: 0 = fp32 to Cf; 2 = single bf16 to Chi.
// ---------------------------------------------------------------------------
struct SegPtrs { const ushort* a[3]; const ushort* b[3]; };

template<int NSEG, int KD, int OUTMODE, bool RELU, bool BIAS>
__global__ __launch_bounds__(256)
void gemm_mfma(SegPtrs segs, const float* __restrict__ bias,
               float* __restrict__ Cf, ushort* __restrict__ Chi) {
  constexpr int NK = KD / 32;
  constexpr int TS = NSEG * NK;
  __shared__ ushort As[2][4096];
  __shared__ ushort Bs[2][4096];
  const int tid  = threadIdx.x;
  const int lane = tid & 63;
  const int w    = tid >> 6;
  const int wr   = w >> 1, wc = w & 1;
  const int m0   = blockIdx.x * 128;
  const int n0   = blockIdx.y * 128;
  const int arow = tid >> 2;
  const int acol = (tid & 3) * 8;
  const int fr   = lane & 15;
  const int fq   = lane >> 4;

  f32x4 acc[4][4] = {};

  auto stage = [&](const ushort* Aseg, const ushort* Bseg, int kk, int db) {
#pragma unroll
    for (int i = 0; i < 2; ++i) {
      const ushort* ga = Aseg + (size_t)(m0 + arow + 64 * i) * KD + kk + acol;
      const ushort* gb = Bseg + (size_t)(n0 + arow + 64 * i) * KD + kk + acol;
      __builtin_amdgcn_global_load_lds((gvoid_t*)ga,
          (lvoid_t*)(&As[db][i * 2048 + w * 512]), 16, 0, 0);
      __builtin_amdgcn_global_load_lds((gvoid_t*)gb,
          (lvoid_t*)(&Bs[db][i * 2048 + w * 512]), 16, 0, 0);
    }
  };

  stage(segs.a[0], segs.b[0], 0, 0);
  __syncthreads();

#pragma unroll
  for (int ts = 0; ts < TS; ++ts) {
    const int db = ts & 1;
    if (ts + 1 < TS) {
      const int s2 = (ts + 1) / NK;
      const int k2 = (ts + 1) % NK;
      stage(segs.a[s2], segs.b[s2], k2 * 32, db ^ 1);
    }
    bf16x8 bfr[4];
#pragma unroll
    for (int nf = 0; nf < 4; ++nf)
      bfr[nf] = *reinterpret_cast<const bf16x8*>(&Bs[db][(wc * 64 + nf * 16 + fr) * 32 + fq * 8]);
#pragma unroll
    for (int mf = 0; mf < 4; ++mf) {
      bf16x8 af = *reinterpret_cast<const bf16x8*>(&As[db][(wr * 64 + mf * 16 + fr) * 32 + fq * 8]);
#pragma unroll
      for (int nf = 0; nf < 4; ++nf)
        acc[mf][nf] = __builtin_amdgcn_mfma_f32_16x16x32_bf16(af, bfr[nf], acc[mf][nf], 0, 0, 0);
    }
    __syncthreads();
  }

  // epilogue: C/D layout col=lane&15, row=(lane>>4)*4+reg  [verified m89]
#pragma unroll
  for (int mf = 0; mf < 4; ++mf) {
#pragma unroll
    for (int nf = 0; nf < 4; ++nf) {
      const int col = n0 + wc * 64 + nf * 16 + fr;
      float bv = 0.f;
      if constexpr (BIAS) bv = bias[col];
#pragma unroll
      for (int r = 0; r < 4; ++r) {
        const int row = m0 + wr * 64 + mf * 16 + fq * 4 + r;
        float v = acc[mf][nf][r] + bv;
        if constexpr (RELU) v = fmaxf(v, 0.f);
        const size_t o = (size_t)row * Hd + col;
        if constexpr (OUTMODE == 0) Cf[o] = v;
        else                        Chi[o] = bf_rne(v);
      }
    }
  }
}

// ---------------------------------------------------------------------------
// nei with precomputed Z: NEI[m,h] = sum_{k<nn} relu(T[ai[k]] + Z[bi[k]])
// Thread owns an h-QUAD (uint2 loads, fully coalesced per wave). All gathers
// issued up front (clamped indices, branch-free).
// ---------------------------------------------------------------------------
__global__ __launch_bounds__(256)
void nei_z(const ushort* __restrict__ T, const ushort* __restrict__ Z,
           const int* __restrict__ atom_graph, const int* __restrict__ bond_graph,
           const int* __restrict__ num_nbs, ushort* __restrict__ NEI) {
  const int tid = threadIdx.x;
  const int hq = tid & 63;
  const int rp = tid >> 6;
  int bid = blockIdx.x;
  bid = (bid & 7) * (gridDim.x >> 3) + (bid >> 3);   // XCD swizzle (4096%8==0)
  const int m0 = bid * 8;
  const int h0 = hq * 4;

#pragma unroll
  for (int j = 0; j < 2; ++j) {
    const int m = m0 + j * 4 + rp;
    const int b = m >> 9;
    const int nn = num_nbs[m];
    int ai[MNB], bi[MNB];
#pragma unroll
    for (int k = 0; k < MNB; ++k) {
      ai[k] = atom_graph[((size_t)m * MNB + k) * 2 + 1];
      bi[k] = bond_graph[((size_t)m * MNB + k) * 2 + 1];
    }
#pragma unroll
    for (int k = 1; k < MNB; ++k) {          // clamp (nn>=1 always)
      ai[k] = (k < nn) ? ai[k] : ai[0];
      bi[k] = (k < nn) ? bi[k] : bi[0];
    }
    uint2 tv[MNB], zv[MNB];
#pragma unroll
    for (int k = 0; k < MNB; ++k) {
      tv[k] = *reinterpret_cast<const uint2*>(&T[(((size_t)b << 9) + ai[k]) * Hd + h0]);
      zv[k] = *reinterpret_cast<const uint2*>(&Z[((size_t)b * NBb + bi[k]) * Hd + h0]);
    }
    float a0 = 0.f, a1 = 0.f, a2 = 0.f, a3 = 0.f;
#pragma unroll
    for (int k = 0; k < MNB; ++k) {
      if (k < nn) {   // wave-uniform
        a0 += fmaxf(__uint_as_float(tv[k].x << 16)        + __uint_as_float(zv[k].x << 16), 0.f);
        a1 += fmaxf(__uint_as_float(tv[k].x & 0xffff0000u) + __uint_as_float(zv[k].x & 0xffff0000u), 0.f);
        a2 += fmaxf(__uint_as_float(tv[k].y << 16)        + __uint_as_float(zv[k].y << 16), 0.f);
        a3 += fmaxf(__uint_as_float(tv[k].y & 0xffff0000u) + __uint_as_float(zv[k].y & 0xffff0000u), 0.f);
      }
    }
    uint2 o;
    o.x = (unsigned)bf_rne(a0) | ((unsigned)bf_rne(a1) << 16);
    o.y = (unsigned)bf_rne(a2) | ((unsigned)bf_rne(a3) << 16);
    *reinterpret_cast<uint2*>(&NEI[(size_t)m * Hd + h0]) = o;
  }
}

// ---------------------------------------------------------------------------
// Fallback nei (recomputes bond dots) — used only if ws too small for Z.
// ---------------------------------------------------------------------------
__global__ __launch_bounds__(256)
void nei_fb(const ushort* __restrict__ T, const float* __restrict__ input_bond,
            const int* __restrict__ atom_graph, const int* __restrict__ bond_graph,
            const int* __restrict__ num_nbs,
            const float* __restrict__ W_U2, const float* __restrict__ b_U2,
            ushort* __restrict__ NEI) {
  const int tid = threadIdx.x;
  const int hp = tid & 127;
  const int rp = tid >> 7;
  int bid = blockIdx.x;
  bid = (bid & 7) * (gridDim.x >> 3) + (bid >> 3);
  const int m0 = bid * 8;
  const int h0 = hp * 2;

  float wb0[Ed], wb1[Ed];
#pragma unroll
  for (int e = 0; e < Ed; ++e) {
    wb0[e] = W_U2[(size_t)(Hd + e) * Hd + h0];
    wb1[e] = W_U2[(size_t)(Hd + e) * Hd + h0 + 1];
  }
  const float b20 = b_U2[h0], b21 = b_U2[h0 + 1];

#pragma unroll
  for (int j = 0; j < 4; ++j) {
    const int m = m0 + j * 2 + rp;
    const int b = m >> 9;
    const int nn = num_nbs[m];
    int ai[MNB], bi[MNB];
#pragma unroll
    for (int k = 0; k < MNB; ++k) {
      ai[k] = atom_graph[((size_t)m * MNB + k) * 2 + 1];
      bi[k] = bond_graph[((size_t)m * MNB + k) * 2 + 1];
    }
#pragma unroll
    for (int k = 1; k < MNB; ++k) {
      ai[k] = (k < nn) ? ai[k] : ai[0];
      bi[k] = (k < nn) ? bi[k] : bi[0];
    }
    unsigned tv[MNB];
#pragma unroll
    for (int k = 0; k < MNB; ++k)
      tv[k] = *reinterpret_cast<const unsigned*>(
          &T[(((size_t)b << 9) + (size_t)ai[k]) * Hd + h0]);

    float acc0 = 0.f, acc1 = 0.f;
#pragma unroll
    for (int k = 0; k < MNB; ++k) {
      const float* bp = input_bond + ((size_t)b * NBb + bi[k]) * Ed;
      float d0 = b20, d1 = b21;
#pragma unroll
      for (int e = 0; e < Ed; ++e) {
        const float f = bp[e];
        d0 = fmaf(f, wb0[e], d0);
        d1 = fmaf(f, wb1[e], d1);
      }
      const float v0 = bf_f((ushort)(tv[k] & 0xffffu)) + d0;
      const float v1 = bf_f((ushort)(tv[k] >> 16)) + d1;
      if (k < nn) { acc0 += fmaxf(v0, 0.f); acc1 += fmaxf(v1, 0.f); }
    }
    const unsigned o = (unsigned)bf_rne(acc0) | ((unsigned)bf_rne(acc1) << 16);
    *reinterpret_cast<unsigned*>(&NEI[(size_t)m * Hd + h0]) = o;
  }
}

extern "C" void kernel_launch(void* const* d_in, const int* in_sizes, int n_in,
                              void* d_out, int out_size, void* d_ws, size_t ws_size,
                              hipStream_t stream) {
  const float* input_atom = (const float*)d_in[0];
  const float* input_bond = (const float*)d_in[1];
  const int*   atom_graph = (const int*)d_in[2];
  const int*   bond_graph = (const int*)d_in[3];
  const int*   num_nbs    = (const int*)d_in[4];
  const float* W_atom     = (const float*)d_in[5];
  const float* W_U2       = (const float*)d_in[6];
  const float* b_U2       = (const float*)d_in[7];
  const float* W_U1       = (const float*)d_in[8];
  const float* b_U1       = (const float*)d_in[9];

  const size_t SL = (size_t)Mrows * Hd;          // 8,388,608 ushorts = 16.78 MB
  // ws (ushorts): AFa, AFb, weights, {Apad hi/lo  ∪  Z}
  ushort* AFa  = (ushort*)d_ws;
  ushort* AFb  = AFa + SL;
  ushort* w2h  = AFb + SL;
  ushort* w1ah = w2h  + 256 * 256;
  ushort* w1bh = w1ah + 256 * 256;
  ushort* wah  = w1bh + 256 * 256;
  ushort* wal  = wah  + 256 * Kpad;
  ushort* apz  = wal  + 256 * Kpad;              // union region
  ushort* Apadh = apz;
  ushort* Apadl = apz + (size_t)Mrows * Kpad;
  ushort* Zbuf  = apz;                           // overwrites Apad after embed

  const size_t zend = ((size_t)(apz - AFa) + (size_t)NBrows * Hd) * sizeof(ushort);
  const size_t aend = ((size_t)(apz - AFa) + 2 * (size_t)Mrows * Kpad) * sizeof(ushort);
  const bool useZ = (ws_size >= zend) && (ws_size >= aend);   // 53.7 MB — fits 64 MiB

  // T in d_out lo half; NEI in d_out hi half (depths 0,1) / AFb (depth 2).
  ushort* Tbf   = (ushort*)d_out;
  ushort* NEI01 = (ushort*)d_out + SL;

  const dim3 blk(256);
  const dim3 gG(Mrows / 128, 2);

  prep_weights<<<256, 256, 0, stream>>>(W_U2, W_U1, w2h, w1ah, w1bh);
  prep_watom<<<256, 128, 0, stream>>>(W_atom, wah, wal);
  conv_atom<<<Mrows / 2, 192, 0, stream>>>(input_atom, Apadh, Apadl);

  // embed: AF0 = input_atom @ W_atom (3 split segs, K=96) -> AFa (single bf16)
  {
    SegPtrs se{};
    se.a[0] = Apadh; se.a[1] = Apadl; se.a[2] = Apadh;
    se.b[0] = wah;   se.b[1] = wah;   se.b[2] = wal;
    gemm_mfma<3, Kpad, 2, false, false><<<gG, blk, 0, stream>>>(se, nullptr, nullptr, AFa);
  }
  if (useZ)   // Z overwrites Apad region — must follow embed
    zprep<<<NBrows / 8, 256, 0, stream>>>(input_bond, W_U2, b_U2, Zbuf);

  ushort* AFcur = AFa;
  ushort* AFnxt = AFb;
  for (int d = 0; d < 3; ++d) {
    // T = AF @ W2 (1 seg) -> bf16 in d_out lo half
    SegPtrs st{};
    st.a[0] = AFcur; st.b[0] = w2h;
    gemm_mfma<1, Hd, 2, false, false><<<gG, blk, 0, stream>>>(st, nullptr, nullptr, Tbf);

    ushort* NEIbuf = (d < 2) ? NEI01 : AFnxt;    // depth 2: AFnxt(=AFb) holds dead AF1
    if (useZ)
      nei_z<<<Mrows / 8, blk, 0, stream>>>(Tbf, Zbuf, atom_graph, bond_graph,
                                           num_nbs, NEIbuf);
    else
      nei_fb<<<Mrows / 8, blk, 0, stream>>>(Tbf, input_bond, atom_graph, bond_graph,
                                            num_nbs, W_U2, b_U2, NEIbuf);

    // AF' = relu(AF@W1a + NEI@W1b + b1): 2 segs
    SegPtrs su{};
    su.a[0] = AFcur;  su.a[1] = NEIbuf;
    su.b[0] = w1ah;   su.b[1] = w1bh;
    if (d < 2) {
      gemm_mfma<2, Hd, 2, true, true><<<gG, blk, 0, stream>>>(su, b_U1, nullptr, AFnxt);
      ushort* t = AFcur; AFcur = AFnxt; AFnxt = t;
    } else {
      gemm_mfma<2, Hd, 0, true, true><<<gG, blk, 0, stream>>>(su, b_U1, (float*)d_out, nullptr);
    }
  }
  // d_out holds the final atom_features (fp32).
}

// Round 6
// 193.986 us; speedup vs baseline: 4.3039x; 1.0585x over previous
//
#include <hip/hip_runtime.h>

// Problem constants (WLN_Edit): B=64, N=512, NB=600, A=89, E=5, H=256, MAX_NB=10, DEPTH=3
constexpr int Bb   = 64;
constexpr int Nn   = 512;
constexpr int NBb  = 600;
constexpr int Ad   = 89;
constexpr int Ed   = 5;
constexpr int Hd   = 256;
constexpr int MNB  = 10;
constexpr int Mrows  = Bb * Nn;    // 32768
constexpr int NBrows = Bb * NBb;   // 38400
constexpr int Kpad   = 96;

typedef __bf16 bf16x8 __attribute__((ext_vector_type(8)));
typedef float  f32x4  __attribute__((ext_vector_type(4)));

typedef __attribute__((address_space(1))) const void gvoid_t;
typedef __attribute__((address_space(3))) void lvoid_t;

__device__ inline ushort bf_rne(float x) {
  unsigned u = __float_as_uint(x);
  unsigned r = (u + 0x7fffu + ((u >> 16) & 1u)) >> 16;
  return (ushort)r;
}
__device__ inline float bf_f(ushort h) { return __uint_as_float(((unsigned)h) << 16); }

// ---------------------------------------------------------------------------
// Mega-prep: one launch, sections by blockIdx.x.
//  S0: input_atom -> Apadh (single bf16, padded [32768][96])
//  S1: Z[b,i,h] = input_bond@W_U2[256:] + b_U2 (bf16)
//  S2: PIdx[m*10+k] = (ai<<16)|bi  (both graphs' last dim packed)
//  S3: w2h/w1ah/w1bh: bf16 weight panels transposed [n][k]
//  S4: Wcomb = W_atom @ {W2a, W1a} -> hi/lo bf16 transposed+padded [256][96]
// ---------------------------------------------------------------------------
constexpr int S0 = Mrows * Kpad / 256;   // 12288
constexpr int S1 = NBrows / 8;           // 4800
constexpr int S2 = Mrows * MNB / 256;    // 1280
constexpr int S3 = 256;
constexpr int S4 = Hd * Kpad / 256;      // 96

__global__ __launch_bounds__(256)
void megaprep(const float* __restrict__ input_atom, const float* __restrict__ input_bond,
              const int* __restrict__ atom_graph, const int* __restrict__ bond_graph,
              const float* __restrict__ W_atom, const float* __restrict__ W_U2,
              const float* __restrict__ b_U2, const float* __restrict__ W_U1,
              ushort* __restrict__ Apadh, ushort* __restrict__ Z, uint* __restrict__ PIdx,
              ushort* __restrict__ w2h, ushort* __restrict__ w1ah, ushort* __restrict__ w1bh,
              ushort* __restrict__ w2ch, ushort* __restrict__ w2cl,
              ushort* __restrict__ w1ch, ushort* __restrict__ w1cl) {
  const int blk = blockIdx.x;
  const int tid = threadIdx.x;
  if (blk < S0) {                                   // conv_atom
    const int e = blk * 256 + tid;                  // [m][96] linear
    const int m = e / Kpad, c = e - m * Kpad;
    Apadh[e] = bf_rne(c < Ad ? input_atom[(size_t)m * Ad + c] : 0.f);
  } else if (blk < S0 + S1) {                       // zprep
    const int r0 = (blk - S0) * 8;
    const int h = tid;
    float w[Ed];
#pragma unroll
    for (int e = 0; e < Ed; ++e) w[e] = W_U2[(size_t)(Hd + e) * Hd + h];
    const float b2 = b_U2[h];
#pragma unroll
    for (int j = 0; j < 8; ++j) {
      const int r = r0 + j;
      const float* bp = input_bond + (size_t)r * Ed;
      float d = b2;
#pragma unroll
      for (int e = 0; e < Ed; ++e) d = fmaf(bp[e], w[e], d);
      Z[(size_t)r * Hd + h] = bf_rne(d);
    }
  } else if (blk < S0 + S1 + S2) {                  // idxpack
    const int i = (blk - S0 - S1) * 256 + tid;      // i = m*10+k
    const uint ai = (uint)atom_graph[(size_t)i * 2 + 1];
    const uint bi = (uint)bond_graph[(size_t)i * 2 + 1];
    PIdx[i] = (ai << 16) | bi;
  } else if (blk < S0 + S1 + S2 + S3) {             // transposed weight panels
    const int n = blk - S0 - S1 - S2;
    const int k = tid;
    const size_t o = (size_t)n * 256 + k;
    w2h[o]  = bf_rne(W_U2[(size_t)k * Hd + n]);
    w1ah[o] = bf_rne(W_U1[(size_t)k * Hd + n]);
    w1bh[o] = bf_rne(W_U1[(size_t)(k + 256) * Hd + n]);
  } else {                                          // Wcomb = W_atom @ {W2a,W1a}
    const int e = (blk - S0 - S1 - S2 - S3) * 256 + tid;   // e = n*96+k
    const int n = e / Kpad, k = e - n * Kpad;
    float s2 = 0.f, s1 = 0.f;
    if (k < Ad) {
      for (int j = 0; j < Hd; ++j) {
        const float wa = W_atom[(size_t)k * Hd + j];
        s2 = fmaf(wa, W_U2[(size_t)j * Hd + n], s2);
        s1 = fmaf(wa, W_U1[(size_t)j * Hd + n], s1);
      }
    }
    ushort h = bf_rne(s2); w2ch[e] = h; w2cl[e] = bf_rne(s2 - bf_f(h));
    h = bf_rne(s1);        w1ch[e] = h; w1cl[e] = bf_rne(s1 - bf_f(h));
  }
}

// ---------------------------------------------------------------------------
// Fused TU GEMM: T = sum_seg A@Bt^T (bf16 out), P = sum_seg A@Bp^T + b_U1 (bf16).
// BM=128, BN=64, BK=32, 4 waves (2M x 2N, per-wave 64x32 per product).
// 2-phase double-buffered, global_load_lds(16B), 1 barrier per K-step.
// ---------------------------------------------------------------------------
struct TUSegs { const ushort* a[2]; const ushort* bt[2]; const ushort* bp[2]; };

template<int NSEG, int KD>
__global__ __launch_bounds__(256)
void gemm_tu(TUSegs segs, const float* __restrict__ bias,
             ushort* __restrict__ Tout, ushort* __restrict__ Pout) {
  constexpr int NK = KD / 32;
  constexpr int TS = NSEG * NK;
  __shared__ ushort As[2][4096];
  __shared__ ushort Bt[2][2048];
  __shared__ ushort Bp[2][2048];
  const int tid  = threadIdx.x;
  const int lane = tid & 63;
  const int w    = tid >> 6;
  const int wr   = w >> 1, wc = w & 1;
  const int m0   = blockIdx.x * 128;
  const int n0   = blockIdx.y * 64;
  const int arow = tid >> 2;          // 0..63
  const int acol = (tid & 3) * 8;
  const int fr   = lane & 15;
  const int fq   = lane >> 4;

  f32x4 accT[4][2] = {};
  f32x4 accP[4][2] = {};

  auto stage = [&](const ushort* Aseg, const ushort* Bts, const ushort* Bps,
                   int kk, int db) {
#pragma unroll
    for (int i = 0; i < 2; ++i) {
      const ushort* ga = Aseg + (size_t)(m0 + arow + 64 * i) * KD + kk + acol;
      __builtin_amdgcn_global_load_lds((gvoid_t*)ga,
          (lvoid_t*)(&As[db][i * 2048 + w * 512]), 16, 0, 0);
    }
    const ushort* gt = Bts + (size_t)(n0 + arow) * KD + kk + acol;
    __builtin_amdgcn_global_load_lds((gvoid_t*)gt,
        (lvoid_t*)(&Bt[db][w * 512]), 16, 0, 0);
    const ushort* gp = Bps + (size_t)(n0 + arow) * KD + kk + acol;
    __builtin_amdgcn_global_load_lds((gvoid_t*)gp,
        (lvoid_t*)(&Bp[db][w * 512]), 16, 0, 0);
  };

  stage(segs.a[0], segs.bt[0], segs.bp[0], 0, 0);
  __syncthreads();

#pragma unroll
  for (int ts = 0; ts < TS; ++ts) {
    const int db = ts & 1;
    if (ts + 1 < TS) {
      const int s2 = (ts + 1) / NK;
      const int k2 = (ts + 1) % NK;
      stage(segs.a[s2], segs.bt[s2], segs.bp[s2], k2 * 32, db ^ 1);
    }
    bf16x8 bt_[2], bp_[2];
#pragma unroll
    for (int nf = 0; nf < 2; ++nf) {
      bt_[nf] = *reinterpret_cast<const bf16x8*>(&Bt[db][(wc * 32 + nf * 16 + fr) * 32 + fq * 8]);
      bp_[nf] = *reinterpret_cast<const bf16x8*>(&Bp[db][(wc * 32 + nf * 16 + fr) * 32 + fq * 8]);
    }
#pragma unroll
    for (int mf = 0; mf < 4; ++mf) {
      bf16x8 af = *reinterpret_cast<const bf16x8*>(&As[db][(wr * 64 + mf * 16 + fr) * 32 + fq * 8]);
#pragma unroll
      for (int nf = 0; nf < 2; ++nf) {
        accT[mf][nf] = __builtin_amdgcn_mfma_f32_16x16x32_bf16(af, bt_[nf], accT[mf][nf], 0, 0, 0);
        accP[mf][nf] = __builtin_amdgcn_mfma_f32_16x16x32_bf16(af, bp_[nf], accP[mf][nf], 0, 0, 0);
      }
    }
    __syncthreads();
  }

#pragma unroll
  for (int mf = 0; mf < 4; ++mf) {
#pragma unroll
    for (int nf = 0; nf < 2; ++nf) {
      const int col = n0 + wc * 32 + nf * 16 + fr;
      const float bv = bias[col];
#pragma unroll
      for (int r = 0; r < 4; ++r) {
        const int row = m0 + wr * 64 + mf * 16 + fq * 4 + r;
        Tout[(size_t)row * Hd + col] = bf_rne(accT[mf][nf][r]);
        Pout[(size_t)row * Hd + col] = bf_rne(accP[mf][nf][r] + bv);
      }
    }
  }
}

// ---------------------------------------------------------------------------
// MFMA GEMM (128x128, 4 waves): C = op( sum_seg A_seg @ B_seg^T [+ Pin] )
// OUTMODE: 0 = fp32 to Cf; 2 = bf16 to Chi.  CLOAD: add bf16 Pin tile.
// ---------------------------------------------------------------------------
struct SegPtrs { const ushort* a[2]; const ushort* b[2]; };

template<int NSEG, int KD, int OUTMODE, bool RELU, bool BIAS, bool CLOAD>
__global__ __launch_bounds__(256)
void gemm_mfma(SegPtrs segs, const float* __restrict__ bias,
               const ushort* __restrict__ Pin,
               float* __restrict__ Cf, ushort* __restrict__ Chi) {
  constexpr int NK = KD / 32;
  constexpr int TS = NSEG * NK;
  __shared__ ushort As[2][4096];
  __shared__ ushort Bs[2][4096];
  const int tid  = threadIdx.x;
  const int lane = tid & 63;
  const int w    = tid >> 6;
  const int wr   = w >> 1, wc = w & 1;
  const int m0   = blockIdx.x * 128;
  const int n0   = blockIdx.y * 128;
  const int arow = tid >> 2;
  const int acol = (tid & 3) * 8;
  const int fr   = lane & 15;
  const int fq   = lane >> 4;

  f32x4 acc[4][4] = {};

  auto stage = [&](const ushort* Aseg, const ushort* Bseg, int kk, int db) {
#pragma unroll
    for (int i = 0; i < 2; ++i) {
      const ushort* ga = Aseg + (size_t)(m0 + arow + 64 * i) * KD + kk + acol;
      const ushort* gb = Bseg + (size_t)(n0 + arow + 64 * i) * KD + kk + acol;
      __builtin_amdgcn_global_load_lds((gvoid_t*)ga,
          (lvoid_t*)(&As[db][i * 2048 + w * 512]), 16, 0, 0);
      __builtin_amdgcn_global_load_lds((gvoid_t*)gb,
          (lvoid_t*)(&Bs[db][i * 2048 + w * 512]), 16, 0, 0);
    }
  };

  stage(segs.a[0], segs.b[0], 0, 0);
  __syncthreads();

#pragma unroll
  for (int ts = 0; ts < TS; ++ts) {
    const int db = ts & 1;
    if (ts + 1 < TS) {
      const int s2 = (ts + 1) / NK;
      const int k2 = (ts + 1) % NK;
      stage(segs.a[s2], segs.b[s2], k2 * 32, db ^ 1);
    }
    bf16x8 bfr[4];
#pragma unroll
    for (int nf = 0; nf < 4; ++nf)
      bfr[nf] = *reinterpret_cast<const bf16x8*>(&Bs[db][(wc * 64 + nf * 16 + fr) * 32 + fq * 8]);
#pragma unroll
    for (int mf = 0; mf < 4; ++mf) {
      bf16x8 af = *reinterpret_cast<const bf16x8*>(&As[db][(wr * 64 + mf * 16 + fr) * 32 + fq * 8]);
#pragma unroll
      for (int nf = 0; nf < 4; ++nf)
        acc[mf][nf] = __builtin_amdgcn_mfma_f32_16x16x32_bf16(af, bfr[nf], acc[mf][nf], 0, 0, 0);
    }
    __syncthreads();
  }

#pragma unroll
  for (int mf = 0; mf < 4; ++mf) {
#pragma unroll
    for (int nf = 0; nf < 4; ++nf) {
      const int col = n0 + wc * 64 + nf * 16 + fr;
      float bv = 0.f;
      if constexpr (BIAS) bv = bias[col];
#pragma unroll
      for (int r = 0; r < 4; ++r) {
        const int row = m0 + wr * 64 + mf * 16 + fq * 4 + r;
        float v = acc[mf][nf][r] + bv;
        if constexpr (CLOAD) v += bf_f(Pin[(size_t)row * Hd + col]);
        if constexpr (RELU) v = fmaxf(v, 0.f);
        const size_t o = (size_t)row * Hd + col;
        if constexpr (OUTMODE == 0) Cf[o] = v;
        else                        Chi[o] = bf_rne(v);
      }
    }
  }
}

// ---------------------------------------------------------------------------
// nei: NEI[m,h] = sum_{k<nn} relu(T[ai[k]] + Z[bi[k]]), packed indices,
// h-oct threads (uint4 loads), 5+5 neighbor chunks. 8 rows/block.
// ---------------------------------------------------------------------------
__global__ __launch_bounds__(256)
void nei_z(const ushort* __restrict__ T, const ushort* __restrict__ Z,
           const uint* __restrict__ PIdx, const int* __restrict__ num_nbs,
           ushort* __restrict__ NEI) {
  const int ho = threadIdx.x & 31;     // h-oct: 8 bf16 = 16B
  const int rp = threadIdx.x >> 5;     // 0..7 row within block
  int bid = blockIdx.x;
  bid = (bid & 7) * (gridDim.x >> 3) + (bid >> 3);   // XCD swizzle (4096%8==0)
  const int m = bid * 8 + rp;
  const int b = m >> 9;
  const int h0 = ho * 8;
  const int nn = num_nbs[m];

  uint pk[MNB];
#pragma unroll
  for (int q = 0; q < 5; ++q) {        // 5x uint2 (8B-aligned: m*40 % 8 == 0)
    const uint2 u = *reinterpret_cast<const uint2*>(&PIdx[(size_t)m * MNB + q * 2]);
    pk[q * 2] = u.x; pk[q * 2 + 1] = u.y;
  }
  int ai[MNB], bi[MNB];
#pragma unroll
  for (int k = 0; k < MNB; ++k) { ai[k] = (int)(pk[k] >> 16); bi[k] = (int)(pk[k] & 0xffffu); }
#pragma unroll
  for (int k = 1; k < MNB; ++k) {      // clamp (nn>=1 always)
    ai[k] = (k < nn) ? ai[k] : ai[0];
    bi[k] = (k < nn) ? bi[k] : bi[0];
  }

  float acc[8] = {};
#pragma unroll
  for (int ch = 0; ch < 2; ++ch) {
    uint4 tv[5], zv[5];
#pragma unroll
    for (int k5 = 0; k5 < 5; ++k5) {
      const int k = ch * 5 + k5;
      tv[k5] = *reinterpret_cast<const uint4*>(&T[(((size_t)b << 9) + ai[k]) * Hd + h0]);
      zv[k5] = *reinterpret_cast<const uint4*>(&Z[((size_t)b * NBb + bi[k]) * Hd + h0]);
    }
#pragma unroll
    for (int k5 = 0; k5 < 5; ++k5) {
      const int k = ch * 5 + k5;
      const uint tw[4] = {tv[k5].x, tv[k5].y, tv[k5].z, tv[k5].w};
      const uint zw[4] = {zv[k5].x, zv[k5].y, zv[k5].z, zv[k5].w};
      if (k < nn) {
#pragma unroll
        for (int q = 0; q < 4; ++q) {
          acc[q * 2]     += fmaxf(__uint_as_float(tw[q] << 16) + __uint_as_float(zw[q] << 16), 0.f);
          acc[q * 2 + 1] += fmaxf(__uint_as_float(tw[q] & 0xffff0000u) + __uint_as_float(zw[q] & 0xffff0000u), 0.f);
        }
      }
    }
  }
  uint4 o;
  o.x = (uint)bf_rne(acc[0]) | ((uint)bf_rne(acc[1]) << 16);
  o.y = (uint)bf_rne(acc[2]) | ((uint)bf_rne(acc[3]) << 16);
  o.z = (uint)bf_rne(acc[4]) | ((uint)bf_rne(acc[5]) << 16);
  o.w = (uint)bf_rne(acc[6]) | ((uint)bf_rne(acc[7]) << 16);
  *reinterpret_cast<uint4*>(&NEI[(size_t)m * Hd + h0]) = o;
}

extern "C" void kernel_launch(void* const* d_in, const int* in_sizes, int n_in,
                              void* d_out, int out_size, void* d_ws, size_t ws_size,
                              hipStream_t stream) {
  const float* input_atom = (const float*)d_in[0];
  const float* input_bond = (const float*)d_in[1];
  const int*   atom_graph = (const int*)d_in[2];
  const int*   bond_graph = (const int*)d_in[3];
  const int*   num_nbs    = (const int*)d_in[4];
  const float* W_atom     = (const float*)d_in[5];
  const float* W_U2       = (const float*)d_in[6];
  const float* b_U2       = (const float*)d_in[7];
  const float* W_U1       = (const float*)d_in[8];
  const float* b_U1       = (const float*)d_in[9];

  const size_t SL = (size_t)Mrows * Hd;            // 8,388,608 ushorts
  // ws layout (61.4 MB total): AFa | AFb(NEI) | PIdx | panels | Apadh | Z
  ushort* AFa  = (ushort*)d_ws;
  ushort* AFb  = AFa + SL;
  uint*   PIdx = (uint*)(AFb + SL);
  ushort* w2h  = (ushort*)(PIdx + (size_t)Mrows * MNB);
  ushort* w1ah = w2h  + 256 * 256;
  ushort* w1bh = w1ah + 256 * 256;
  ushort* w2ch = w1bh + 256 * 256;
  ushort* w2cl = w2ch + Hd * Kpad;
  ushort* w1ch = w2cl + Hd * Kpad;
  ushort* w1cl = w1ch + Hd * Kpad;
  ushort* Apadh= w1cl + Hd * Kpad;
  ushort* Zbuf = Apadh + (size_t)Mrows * Kpad;

  ushort* Tbf = (ushort*)d_out;                    // d_out lo half: T (bf16)
  ushort* Pbf = Tbf + SL;                          // d_out hi half: P (bf16)

  const dim3 blk(256);
  const dim3 gTU(Mrows / 128, Hd / 64);            // (256, 4)
  const dim3 gG (Mrows / 128, Hd / 128);           // (256, 2)

  megaprep<<<S0 + S1 + S2 + S3 + S4, blk, 0, stream>>>(
      input_atom, input_bond, atom_graph, bond_graph, W_atom, W_U2, b_U2, W_U1,
      Apadh, Zbuf, PIdx, w2h, w1ah, w1bh, w2ch, w2cl, w1ch, w1cl);

  // ---- depth 0 (embed folded: T0 = Apad@Wcomb2, P0 = Apad@Wcomb1 + b_U1) ----
  {
    TUSegs t{};
    t.a[0] = Apadh; t.a[1] = Apadh;
    t.bt[0] = w2ch; t.bt[1] = w2cl;
    t.bp[0] = w1ch; t.bp[1] = w1cl;
    gemm_tu<2, Kpad><<<gTU, blk, 0, stream>>>(t, b_U1, Tbf, Pbf);
  }
  nei_z<<<Mrows / 8, blk, 0, stream>>>(Tbf, Zbuf, PIdx, num_nbs, AFb);
  {
    SegPtrs s{};
    s.a[0] = AFb; s.b[0] = w1bh;
    gemm_mfma<1, Hd, 2, true, false, true><<<gG, blk, 0, stream>>>(s, nullptr, Pbf, nullptr, AFa);
  }

  // ---- depth 1 ----
  {
    TUSegs t{};
    t.a[0] = AFa; t.bt[0] = w2h; t.bp[0] = w1ah;
    gemm_tu<1, Hd><<<gTU, blk, 0, stream>>>(t, b_U1, Tbf, Pbf);
  }
  nei_z<<<Mrows / 8, blk, 0, stream>>>(Tbf, Zbuf, PIdx, num_nbs, AFb);
  {
    SegPtrs s{};
    s.a[0] = AFb; s.b[0] = w1bh;
    gemm_mfma<1, Hd, 2, true, false, true><<<gG, blk, 0, stream>>>(s, nullptr, Pbf, nullptr, AFa);
  }

  // ---- depth 2 (exact fp32 output path, unfused) ----
  {
    SegPtrs s{};
    s.a[0] = AFa; s.b[0] = w2h;
    gemm_mfma<1, Hd, 2, false, false, false><<<gG, blk, 0, stream>>>(s, nullptr, nullptr, nullptr, Tbf);
  }
  nei_z<<<Mrows / 8, blk, 0, stream>>>(Tbf, Zbuf, PIdx, num_nbs, AFb);
  {
    SegPtrs s{};
    s.a[0] = AFa; s.a[1] = AFb;
    s.b[0] = w1ah; s.b[1] = w1bh;
    gemm_mfma<2, Hd, 0, true, true, false><<<gG, blk, 0, stream>>>(s, b_U1, nullptr, (float*)d_out, nullptr);
  }
  // d_out holds the final atom_features (fp32).
}